// Round 1
// baseline (1456.230 us; speedup 1.0000x reference)
//
#include <hip/hip_runtime.h>
#include <hip/hip_bf16.h>
#include <math.h>

// ---------------- problem constants ----------------
#define B_   16
#define NQ_  300
#define D_   256
#define NH_  8
#define DH_  32
#define L_   3
#define P_   4
#define FFN_ 1024
#define S_   8400   // 80*80 + 40*40 + 20*20
#define ROWS_ (B_*NQ_)        // 4800
#define NB_   (ROWS_*D_)      // 1228800 floats per (B,NQ,D) buffer

// ---------------- elementwise add (float4) ----------------
__global__ __launch_bounds__(256) void add_kernel(const float* __restrict__ a,
                                                  const float* __restrict__ b,
                                                  float* __restrict__ o, int n4) {
    int i = blockIdx.x * 256 + threadIdx.x;
    if (i < n4) {
        float4 va = ((const float4*)a)[i];
        float4 vb = ((const float4*)b)[i];
        float4 vo = {va.x+vb.x, va.y+vb.y, va.z+vb.z, va.w+vb.w};
        ((float4*)o)[i] = vo;
    }
}

// ---------------- generic tiled fp32 GEMM: C = A(MxK) @ W(KxN) + bias, opt relu ----
#define BM 64
#define BN 64
#define BK 16
__global__ __launch_bounds__(256) void gemm_bias_act(
    const float* __restrict__ A, const float* __restrict__ W,
    const float* __restrict__ bias, float* __restrict__ C,
    int M, int N, int K, int relu)
{
    __shared__ float As[BK][BM + 1];
    __shared__ float Ws[BK][BN + 4];
    int tid = threadIdx.x;
    int bx = blockIdx.x;           // n tile
    int by = blockIdx.y;           // m tile
    int tx = tid & 15;
    int ty = tid >> 4;
    float acc[4][4] = {};
    int arow = tid >> 2;           // 0..63
    int acol = (tid & 3) * 4;      // 0,4,8,12
    int wrow = tid >> 4;           // 0..15
    int wcol = (tid & 15) * 4;     // 0..60
    const int n0 = bx * BN;
    const bool fullN = (n0 + BN <= N);

    for (int k0 = 0; k0 < K; k0 += BK) {
        float4 av = *(const float4*)(A + (size_t)(by*BM + arow)*K + k0 + acol);
        As[acol+0][arow] = av.x;
        As[acol+1][arow] = av.y;
        As[acol+2][arow] = av.z;
        As[acol+3][arow] = av.w;
        if (fullN) {
            float4 wv = *(const float4*)(W + (size_t)(k0 + wrow)*N + n0 + wcol);
            *(float4*)&Ws[wrow][wcol] = wv;
        } else {
            #pragma unroll
            for (int j = 0; j < 4; j++) {
                int c = n0 + wcol + j;
                Ws[wrow][wcol+j] = (c < N) ? W[(size_t)(k0+wrow)*N + c] : 0.f;
            }
        }
        __syncthreads();
        #pragma unroll
        for (int k = 0; k < BK; k++) {
            float a[4], w[4];
            #pragma unroll
            for (int i = 0; i < 4; i++) a[i] = As[k][ty*4+i];
            #pragma unroll
            for (int j = 0; j < 4; j++) w[j] = Ws[k][tx*4+j];
            #pragma unroll
            for (int i = 0; i < 4; i++)
                #pragma unroll
                for (int j = 0; j < 4; j++)
                    acc[i][j] += a[i]*w[j];
        }
        __syncthreads();
    }
    #pragma unroll
    for (int i = 0; i < 4; i++) {
        int r = by*BM + ty*4 + i;
        #pragma unroll
        for (int j = 0; j < 4; j++) {
            int c = n0 + tx*4 + j;
            if (c < N) {
                float vv = acc[i][j] + bias[c];
                if (relu) vv = fmaxf(vv, 0.f);
                C[(size_t)r*N + c] = vv;
            }
        }
    }
}

// ---------------- self attention: one wave per query ----------------
// grid.x = B*NH*75, block = 256 (4 waves, 4 queries)
__global__ __launch_bounds__(256) void self_attn_kernel(
    const float* __restrict__ q, const float* __restrict__ k,
    const float* __restrict__ v, float* __restrict__ sa)
{
    __shared__ float p_lds[4][304];
    __shared__ float q_lds[4][32];
    int bid = blockIdx.x;
    int qt = bid % 75;
    int bh = bid / 75;
    int h = bh & 7;
    int b = bh >> 3;
    int tid = threadIdx.x;
    int w = tid >> 6;
    int lane = tid & 63;
    int query = qt*4 + w;

    if (lane < 32)
        q_lds[w][lane] = q[(size_t)b*NQ_*D_ + (size_t)query*D_ + h*DH_ + lane];
    __syncthreads();

    const float scale = 0.17677669529663687f;   // 1/sqrt(32)
    const float* kbase = k + (size_t)b*NQ_*D_ + h*DH_;
    float s[5];
    float m = -1e30f;
    #pragma unroll
    for (int kk = 0; kk < 5; kk++) {
        int key = kk*64 + lane;
        float sc = -1e30f;
        if (key < NQ_) {
            const float* kr = kbase + (size_t)key*D_;
            float acc = 0.f;
            #pragma unroll
            for (int d = 0; d < DH_; d++) acc += q_lds[w][d] * kr[d];
            sc = acc * scale;
        }
        s[kk] = sc;
        m = fmaxf(m, sc);
    }
    #pragma unroll
    for (int off = 32; off; off >>= 1) m = fmaxf(m, __shfl_xor(m, off));
    float lsum = 0.f;
    #pragma unroll
    for (int kk = 0; kk < 5; kk++) {
        int key = kk*64 + lane;
        if (key < NQ_) {
            float e = __expf(s[kk] - m);
            p_lds[w][key] = e;
            lsum += e;
        }
    }
    #pragma unroll
    for (int off = 32; off; off >>= 1) lsum += __shfl_xor(lsum, off);
    float inv = 1.0f / lsum;
    __syncthreads();

    int half = lane >> 5;
    int d = lane & 31;
    const float* vbase = v + (size_t)b*NQ_*D_ + h*DH_ + d;
    float acc = 0.f;
    for (int key = half; key < NQ_; key += 2)
        acc += p_lds[w][key] * vbase[(size_t)key*D_];
    acc += __shfl_xor(acc, 32);
    if (half == 0)
        sa[(size_t)b*NQ_*D_ + (size_t)query*D_ + h*DH_ + d] = acc * inv;
}

// ---------------- LayerNorm(x + y) ----------------
// grid.x = 1200, block = 256 (4 waves, one row each)
__global__ __launch_bounds__(256) void ln_add_kernel(
    const float* __restrict__ x, const float* __restrict__ y,
    const float* __restrict__ g, const float* __restrict__ bb,
    float* __restrict__ out)
{
    int w = threadIdx.x >> 6, lane = threadIdx.x & 63;
    int row = blockIdx.x*4 + w;
    const float* xr = x + (size_t)row*D_;
    const float* yr = y + (size_t)row*D_;
    float vals[4];
    float s = 0.f;
    #pragma unroll
    for (int i = 0; i < 4; i++) { vals[i] = xr[lane + 64*i] + yr[lane + 64*i]; s += vals[i]; }
    #pragma unroll
    for (int off = 32; off; off >>= 1) s += __shfl_xor(s, off);
    float mean = s * (1.0f/D_);
    float vs = 0.f;
    #pragma unroll
    for (int i = 0; i < 4; i++) { float dd = vals[i]-mean; vs += dd*dd; }
    #pragma unroll
    for (int off = 32; off; off >>= 1) vs += __shfl_xor(vs, off);
    float rstd = rsqrtf(vs*(1.0f/D_) + 1e-5f);
    #pragma unroll
    for (int i = 0; i < 4; i++) {
        int c = lane + 64*i;
        out[(size_t)row*D_ + c] = (vals[i]-mean)*rstd*g[c] + bb[c];
    }
}

// ---------------- softmax over 12 (L*P) per (b,q,h) row, in place -------------
__global__ __launch_bounds__(256) void softmax12_kernel(float* __restrict__ aw, int nrows)
{
    int r = blockIdx.x*256 + threadIdx.x;
    if (r >= nrows) return;
    float* p = aw + (size_t)r*12;
    float v[12];
    float m = -1e30f;
    #pragma unroll
    for (int i = 0; i < 12; i++) { v[i] = p[i]; m = fmaxf(m, v[i]); }
    float s = 0.f;
    #pragma unroll
    for (int i = 0; i < 12; i++) { v[i] = __expf(v[i]-m); s += v[i]; }
    float inv = 1.f/s;
    #pragma unroll
    for (int i = 0; i < 12; i++) p[i] = v[i]*inv;
}

// ---------------- deformable bilinear sampling ----------------
// one thread per (b,q,h,d); 1,228,800 threads
__global__ __launch_bounds__(256) void deform_kernel(
    const float* __restrict__ value, const float* __restrict__ off,
    const float* __restrict__ aw, const float* __restrict__ refp,
    float* __restrict__ dout)
{
    int gid = blockIdx.x*256 + threadIdx.x;
    int d = gid & 31;
    int h = (gid >> 5) & 7;
    int bq = gid >> 8;
    int qq = bq % NQ_;
    int b  = bq / NQ_;

    const int starts[3] = {0, 6400, 8000};
    const int Hs[3] = {80, 40, 20};

    const float* offp = off + ((size_t)(b*NQ_+qq)*NH_ + h)*(L_*P_*2);
    const float* awp  = aw  + ((size_t)(b*NQ_+qq)*NH_ + h)*(L_*P_);
    const float* refq = refp + (size_t)(b*NQ_+qq)*(L_*2);
    const float* vb   = value + (size_t)b*S_*D_ + h*DH_ + d;

    float acc = 0.f;
    #pragma unroll
    for (int l = 0; l < L_; l++) {
        int Hl = Hs[l], Wl = Hs[l];
        float rx = refq[l*2+0], ry = refq[l*2+1];
        const float* vlb = vb + (size_t)starts[l]*D_;
        #pragma unroll
        for (int p = 0; p < P_; p++) {
            float ox = offp[(l*P_+p)*2+0], oy = offp[(l*P_+p)*2+1];
            float a  = awp[l*P_+p];
            float x = (rx + ox/(float)Wl)*(float)Wl - 0.5f;
            float y = (ry + oy/(float)Hl)*(float)Hl - 0.5f;
            float x0 = floorf(x), y0 = floorf(y);
            #pragma unroll
            for (int dy = 0; dy < 2; dy++) {
                #pragma unroll
                for (int dx = 0; dx < 2; dx++) {
                    float xi = x0 + dx, yi = y0 + dy;
                    float wgt = (1.f - fabsf(x-xi))*(1.f - fabsf(y-yi));
                    bool valid = (xi >= 0.f) && (xi < (float)Wl) && (yi >= 0.f) && (yi < (float)Hl);
                    if (valid && wgt != 0.f) {
                        int ix = (int)xi, iy = (int)yi;
                        acc += a * wgt * vlb[(size_t)(iy*Wl + ix)*D_];
                    }
                }
            }
        }
    }
    dout[gid] = acc;
}

// ---------------- launch ----------------
extern "C" void kernel_launch(void* const* d_in, const int* in_sizes, int n_in,
                              void* d_out, int out_size, void* d_ws, size_t ws_size,
                              hipStream_t stream) {
    (void)in_sizes; (void)n_in; (void)out_size; (void)ws_size;
    const float* h_in  = (const float*)d_in[0];
    const float* pos   = (const float*)d_in[1];
    const float* ehs   = (const float*)d_in[2];
    const float* refp  = (const float*)d_in[3];
    // d_in[4] = spatial_shapes (hardcoded)
    const float* wq    = (const float*)d_in[5];
    const float* bq    = (const float*)d_in[6];
    const float* wk    = (const float*)d_in[7];
    const float* bk    = (const float*)d_in[8];
    const float* wv    = (const float*)d_in[9];
    const float* bv    = (const float*)d_in[10];
    const float* wo    = (const float*)d_in[11];
    const float* bo    = (const float*)d_in[12];
    const float* ln1g  = (const float*)d_in[13];
    const float* ln1b  = (const float*)d_in[14];
    const float* w_off = (const float*)d_in[15];
    const float* b_off = (const float*)d_in[16];
    const float* w_aw  = (const float*)d_in[17];
    const float* b_aw  = (const float*)d_in[18];
    const float* w_val = (const float*)d_in[19];
    const float* b_val = (const float*)d_in[20];
    const float* w_out = (const float*)d_in[21];
    const float* b_out = (const float*)d_in[22];
    const float* ln2g  = (const float*)d_in[23];
    const float* ln2b  = (const float*)d_in[24];
    const float* w_fc1 = (const float*)d_in[25];
    const float* b_fc1 = (const float*)d_in[26];
    const float* w_fc2 = (const float*)d_in[27];
    const float* b_fc2 = (const float*)d_in[28];
    const float* ln3g  = (const float*)d_in[29];
    const float* ln3b  = (const float*)d_in[30];
    float* out = (float*)d_out;

    float* ws = (float*)d_ws;
    float* buf_hp   = ws + 0*(size_t)NB_;   // hp / hp2
    float* buf_q    = ws + 1*(size_t)NB_;   // q, later off (921600 < NB)
    float* buf_k    = ws + 2*(size_t)NB_;   // k, later aw  (460800 < NB)
    float* buf_v    = ws + 3*(size_t)NB_;   // v, later dout
    float* buf_sa   = ws + 4*(size_t)NB_;   // sa, later ca
    float* buf_tmp  = ws + 5*(size_t)NB_;   // sa2 / mlp
    float* buf_h1   = ws + 6*(size_t)NB_;
    float* buf_h2   = ws + 7*(size_t)NB_;
    float* buf_fc1  = ws + 8*(size_t)NB_;                 // 4,915,200 floats
    float* buf_val  = ws + 8*(size_t)NB_ + (size_t)ROWS_*FFN_;  // 34,406,400 floats

    const int n4 = NB_/4;
    dim3 blk(256);

    // hp = h + pos
    add_kernel<<<dim3((n4+255)/256), blk, 0, stream>>>(h_in, pos, buf_hp, n4);
    // q,k,v projections
    gemm_bias_act<<<dim3(D_/BN, ROWS_/BM), blk, 0, stream>>>(buf_hp, wq, bq, buf_q, ROWS_, D_, D_, 0);
    gemm_bias_act<<<dim3(D_/BN, ROWS_/BM), blk, 0, stream>>>(buf_hp, wk, bk, buf_k, ROWS_, D_, D_, 0);
    gemm_bias_act<<<dim3(D_/BN, ROWS_/BM), blk, 0, stream>>>(h_in,   wv, bv, buf_v, ROWS_, D_, D_, 0);
    // self attention
    self_attn_kernel<<<dim3(B_*NH_*75), blk, 0, stream>>>(buf_q, buf_k, buf_v, buf_sa);
    // output projection
    gemm_bias_act<<<dim3(D_/BN, ROWS_/BM), blk, 0, stream>>>(buf_sa, wo, bo, buf_tmp, ROWS_, D_, D_, 0);
    // LN1: h1 = LN(h + sa2)
    ln_add_kernel<<<dim3(ROWS_/4), blk, 0, stream>>>(h_in, buf_tmp, ln1g, ln1b, buf_h1);
    // hp2 = h1 + pos
    add_kernel<<<dim3((n4+255)/256), blk, 0, stream>>>(buf_h1, pos, buf_hp, n4);
    // value projection (big GEMM)
    gemm_bias_act<<<dim3(D_/BN, (B_*S_)/BM), blk, 0, stream>>>(ehs, w_val, b_val, buf_val, B_*S_, D_, D_, 0);
    // offsets + attention weights
    gemm_bias_act<<<dim3(192/BN, ROWS_/BM), blk, 0, stream>>>(buf_hp, w_off, b_off, buf_q, ROWS_, 192, D_, 0);
    gemm_bias_act<<<dim3((96+BN-1)/BN, ROWS_/BM), blk, 0, stream>>>(buf_hp, w_aw, b_aw, buf_k, ROWS_, 96, D_, 0);
    softmax12_kernel<<<dim3((ROWS_*NH_+255)/256), blk, 0, stream>>>(buf_k, ROWS_*NH_);
    // deformable sampling
    deform_kernel<<<dim3(NB_/256), blk, 0, stream>>>(buf_val, buf_q, buf_k, refp, buf_v);
    // ca projection
    gemm_bias_act<<<dim3(D_/BN, ROWS_/BM), blk, 0, stream>>>(buf_v, w_out, b_out, buf_sa, ROWS_, D_, D_, 0);
    // LN2
    ln_add_kernel<<<dim3(ROWS_/4), blk, 0, stream>>>(buf_h1, buf_sa, ln2g, ln2b, buf_h2);
    // FFN
    gemm_bias_act<<<dim3(FFN_/BN, ROWS_/BM), blk, 0, stream>>>(buf_h2, w_fc1, b_fc1, buf_fc1, ROWS_, FFN_, D_, 1);
    gemm_bias_act<<<dim3(D_/BN, ROWS_/BM), blk, 0, stream>>>(buf_fc1, w_fc2, b_fc2, buf_tmp, ROWS_, D_, FFN_, 0);
    // LN3 -> out
    ln_add_kernel<<<dim3(ROWS_/4), blk, 0, stream>>>(buf_h2, buf_tmp, ln3g, ln3b, out);
}

// Round 2
// 785.908 us; speedup vs baseline: 1.8529x; 1.8529x over previous
//
#include <hip/hip_runtime.h>
#include <hip/hip_bf16.h>
#include <math.h>

// ---------------- problem constants ----------------
#define B_   16
#define NQ_  300
#define D_   256
#define NH_  8
#define DH_  32
#define L_   3
#define P_   4
#define FFN_ 1024
#define S_   8400   // 80*80 + 40*40 + 20*20
#define ROWS_ (B_*NQ_)        // 4800
#define NB_   (ROWS_*D_)      // 1228800 floats per (B,NQ,D) buffer

typedef __attribute__((ext_vector_type(4))) unsigned short ushort4_t;
typedef __attribute__((ext_vector_type(8))) unsigned short ushort8_t;

__device__ inline unsigned short f2b(float f) {
    __hip_bfloat16 h = __float2bfloat16(f);
    return __builtin_bit_cast(unsigned short, h);
}
__device__ inline float b2f(unsigned short u) {
    union { unsigned u; float f; } c; c.u = ((unsigned)u) << 16; return c.f;
}

// ---------------- elementwise add (float4) ----------------
__global__ __launch_bounds__(256) void add_kernel(const float* __restrict__ a,
                                                  const float* __restrict__ b,
                                                  float* __restrict__ o, int n4) {
    int i = blockIdx.x * 256 + threadIdx.x;
    if (i < n4) {
        float4 va = ((const float4*)a)[i];
        float4 vb = ((const float4*)b)[i];
        float4 vo = {va.x+vb.x, va.y+vb.y, va.z+vb.z, va.w+vb.w};
        ((float4*)o)[i] = vo;
    }
}

// ---------------- generic tiled fp32 GEMM: C = A(MxK) @ W(KxN) + bias, opt relu ----
#define BM 64
#define BN 64
#define BK 16
__global__ __launch_bounds__(256) void gemm_bias_act(
    const float* __restrict__ A, const float* __restrict__ W,
    const float* __restrict__ bias, float* __restrict__ C,
    int M, int N, int K, int relu)
{
    __shared__ float As[BK][BM + 1];
    __shared__ float Ws[BK][BN + 4];
    int tid = threadIdx.x;
    int bx = blockIdx.x;           // n tile
    int by = blockIdx.y;           // m tile
    int tx = tid & 15;
    int ty = tid >> 4;
    float acc[4][4] = {};
    int arow = tid >> 2;           // 0..63
    int acol = (tid & 3) * 4;      // 0,4,8,12
    int wrow = tid >> 4;           // 0..15
    int wcol = (tid & 15) * 4;     // 0..60
    const int n0 = bx * BN;
    const bool fullN = (n0 + BN <= N);

    for (int k0 = 0; k0 < K; k0 += BK) {
        float4 av = *(const float4*)(A + (size_t)(by*BM + arow)*K + k0 + acol);
        As[acol+0][arow] = av.x;
        As[acol+1][arow] = av.y;
        As[acol+2][arow] = av.z;
        As[acol+3][arow] = av.w;
        if (fullN) {
            float4 wv = *(const float4*)(W + (size_t)(k0 + wrow)*N + n0 + wcol);
            *(float4*)&Ws[wrow][wcol] = wv;
        } else {
            #pragma unroll
            for (int j = 0; j < 4; j++) {
                int c = n0 + wcol + j;
                Ws[wrow][wcol+j] = (c < N) ? W[(size_t)(k0+wrow)*N + c] : 0.f;
            }
        }
        __syncthreads();
        #pragma unroll
        for (int k = 0; k < BK; k++) {
            float a[4], w[4];
            #pragma unroll
            for (int i = 0; i < 4; i++) a[i] = As[k][ty*4+i];
            #pragma unroll
            for (int j = 0; j < 4; j++) w[j] = Ws[k][tx*4+j];
            #pragma unroll
            for (int i = 0; i < 4; i++)
                #pragma unroll
                for (int j = 0; j < 4; j++)
                    acc[i][j] += a[i]*w[j];
        }
        __syncthreads();
    }
    #pragma unroll
    for (int i = 0; i < 4; i++) {
        int r = by*BM + ty*4 + i;
        #pragma unroll
        for (int j = 0; j < 4; j++) {
            int c = n0 + tx*4 + j;
            if (c < N) {
                float vv = acc[i][j] + bias[c];
                if (relu) vv = fmaxf(vv, 0.f);
                C[(size_t)r*N + c] = vv;
            }
        }
    }
}

// ---------------- self attention: LDS-staged K/V (bf16), block per (b,h,third) ----
// grid.x = B*NH*3 = 384, block = 256 (4 waves, 25 queries each)
__global__ __launch_bounds__(256) void self_attn_kernel(
    const float* __restrict__ q, const float* __restrict__ k,
    const float* __restrict__ v, float* __restrict__ sa)
{
    __shared__ unsigned short k_lds[300][40];  // bf16, padded: 80B rows, 16B-aligned
    __shared__ unsigned short v_lds[300][32];  // bf16, 64B rows
    __shared__ float q_lds[4][32];
    __shared__ float p_lds[4][304];

    int bid = blockIdx.x;
    int part = bid % 3;            // query third: 0..2
    int bh = bid / 3;
    int h = bh & 7;
    int b = bh >> 3;
    int tid = threadIdx.x;
    int w = tid >> 6;
    int lane = tid & 63;

    // ---- stage K and V (fp32 global -> bf16 LDS), coalesced float4 loads ----
    const size_t base = (size_t)b*NQ_*D_ + h*DH_;
    for (int i = tid; i < 2400; i += 256) {
        int key = i >> 3, seg = i & 7;
        float4 kv = *(const float4*)(k + base + (size_t)key*D_ + seg*4);
        ushort4_t kb = { f2b(kv.x), f2b(kv.y), f2b(kv.z), f2b(kv.w) };
        *(ushort4_t*)&k_lds[key][seg*4] = kb;
        float4 vv = *(const float4*)(v + base + (size_t)key*D_ + seg*4);
        ushort4_t vb = { f2b(vv.x), f2b(vv.y), f2b(vv.z), f2b(vv.w) };
        *(ushort4_t*)&v_lds[key][seg*4] = vb;
    }
    __syncthreads();

    const float scale = 0.17677669529663687f;   // 1/sqrt(32)
    const int q0 = part * 100 + w * 25;

    for (int it = 0; it < 25; ++it) {
        int query = q0 + it;
        // q row -> LDS -> broadcast into 32 VGPRs
        if (lane < 32)
            q_lds[w][lane] = q[base + (size_t)query*D_ + lane];
        float qreg[32];
        #pragma unroll
        for (int j = 0; j < 8; ++j) {
            float4 t = *(const float4*)&q_lds[w][j*4];
            qreg[j*4+0] = t.x; qreg[j*4+1] = t.y;
            qreg[j*4+2] = t.z; qreg[j*4+3] = t.w;
        }

        // ---- QK^T: lane owns keys lane, lane+64, ... ----
        float s[5];
        float m = -1e30f;
        #pragma unroll
        for (int kk = 0; kk < 5; ++kk) {
            int key = kk*64 + lane;
            float sc = -1e30f;
            if (key < NQ_) {
                float acc = 0.f;
                #pragma unroll
                for (int d8 = 0; d8 < 4; ++d8) {
                    ushort8_t kv = *(const ushort8_t*)&k_lds[key][d8*8];
                    #pragma unroll
                    for (int j = 0; j < 8; ++j)
                        acc += qreg[d8*8+j] * b2f(kv[j]);
                }
                sc = acc * scale;
            }
            s[kk] = sc;
            m = fmaxf(m, sc);
        }
        #pragma unroll
        for (int off = 32; off; off >>= 1) m = fmaxf(m, __shfl_xor(m, off));
        float lsum = 0.f;
        #pragma unroll
        for (int kk = 0; kk < 5; ++kk) {
            int key = kk*64 + lane;
            if (key < NQ_) {
                float e = __expf(s[kk] - m);
                p_lds[w][key] = e;
                lsum += e;
            }
        }
        #pragma unroll
        for (int off = 32; off; off >>= 1) lsum += __shfl_xor(lsum, off);
        float inv = 1.0f / lsum;

        // ---- PV: lane covers d = {dg, dg+1}, key-group kg of 4 ----
        int dg = (lane & 15) * 2;
        int kg = lane >> 4;
        float acc0 = 0.f, acc1 = 0.f;
        for (int key = kg; key < NQ_; key += 4) {
            float p = p_lds[w][key];
            unsigned u = *(const unsigned*)&v_lds[key][dg];
            acc0 += p * b2f((unsigned short)(u & 0xffff));
            acc1 += p * b2f((unsigned short)(u >> 16));
        }
        acc0 += __shfl_xor(acc0, 16); acc0 += __shfl_xor(acc0, 32);
        acc1 += __shfl_xor(acc1, 16); acc1 += __shfl_xor(acc1, 32);
        if (lane < 16) {
            float2 o = { acc0 * inv, acc1 * inv };
            *(float2*)&sa[base + (size_t)query*D_ + dg] = o;
        }
    }
}

// ---------------- LayerNorm(x + y) ----------------
// grid.x = 1200, block = 256 (4 waves, one row each)
__global__ __launch_bounds__(256) void ln_add_kernel(
    const float* __restrict__ x, const float* __restrict__ y,
    const float* __restrict__ g, const float* __restrict__ bb,
    float* __restrict__ out)
{
    int w = threadIdx.x >> 6, lane = threadIdx.x & 63;
    int row = blockIdx.x*4 + w;
    const float* xr = x + (size_t)row*D_;
    const float* yr = y + (size_t)row*D_;
    float vals[4];
    float s = 0.f;
    #pragma unroll
    for (int i = 0; i < 4; i++) { vals[i] = xr[lane + 64*i] + yr[lane + 64*i]; s += vals[i]; }
    #pragma unroll
    for (int off = 32; off; off >>= 1) s += __shfl_xor(s, off);
    float mean = s * (1.0f/D_);
    float vs = 0.f;
    #pragma unroll
    for (int i = 0; i < 4; i++) { float dd = vals[i]-mean; vs += dd*dd; }
    #pragma unroll
    for (int off = 32; off; off >>= 1) vs += __shfl_xor(vs, off);
    float rstd = rsqrtf(vs*(1.0f/D_) + 1e-5f);
    #pragma unroll
    for (int i = 0; i < 4; i++) {
        int c = lane + 64*i;
        out[(size_t)row*D_ + c] = (vals[i]-mean)*rstd*g[c] + bb[c];
    }
}

// ---------------- softmax over 12 (L*P) per (b,q,h) row, in place -------------
__global__ __launch_bounds__(256) void softmax12_kernel(float* __restrict__ aw, int nrows)
{
    int r = blockIdx.x*256 + threadIdx.x;
    if (r >= nrows) return;
    float* p = aw + (size_t)r*12;
    float v[12];
    float m = -1e30f;
    #pragma unroll
    for (int i = 0; i < 12; i++) { v[i] = p[i]; m = fmaxf(m, v[i]); }
    float s = 0.f;
    #pragma unroll
    for (int i = 0; i < 12; i++) { v[i] = __expf(v[i]-m); s += v[i]; }
    float inv = 1.f/s;
    #pragma unroll
    for (int i = 0; i < 12; i++) p[i] = v[i]*inv;
}

// ---------------- deformable bilinear sampling ----------------
// one thread per (b,q,h,d); 1,228,800 threads
__global__ __launch_bounds__(256) void deform_kernel(
    const float* __restrict__ value, const float* __restrict__ off,
    const float* __restrict__ aw, const float* __restrict__ refp,
    float* __restrict__ dout)
{
    int gid = blockIdx.x*256 + threadIdx.x;
    int d = gid & 31;
    int h = (gid >> 5) & 7;
    int bq = gid >> 8;
    int qq = bq % NQ_;
    int b  = bq / NQ_;

    const int starts[3] = {0, 6400, 8000};
    const int Hs[3] = {80, 40, 20};

    const float* offp = off + ((size_t)(b*NQ_+qq)*NH_ + h)*(L_*P_*2);
    const float* awp  = aw  + ((size_t)(b*NQ_+qq)*NH_ + h)*(L_*P_);
    const float* refq = refp + (size_t)(b*NQ_+qq)*(L_*2);
    const float* vb   = value + (size_t)b*S_*D_ + h*DH_ + d;

    float acc = 0.f;
    #pragma unroll
    for (int l = 0; l < L_; l++) {
        int Hl = Hs[l], Wl = Hs[l];
        float rx = refq[l*2+0], ry = refq[l*2+1];
        const float* vlb = vb + (size_t)starts[l]*D_;
        #pragma unroll
        for (int p = 0; p < P_; p++) {
            float ox = offp[(l*P_+p)*2+0], oy = offp[(l*P_+p)*2+1];
            float a  = awp[l*P_+p];
            float x = (rx + ox/(float)Wl)*(float)Wl - 0.5f;
            float y = (ry + oy/(float)Hl)*(float)Hl - 0.5f;
            float x0 = floorf(x), y0 = floorf(y);
            #pragma unroll
            for (int dy = 0; dy < 2; dy++) {
                #pragma unroll
                for (int dx = 0; dx < 2; dx++) {
                    float xi = x0 + dx, yi = y0 + dy;
                    float wgt = (1.f - fabsf(x-xi))*(1.f - fabsf(y-yi));
                    bool valid = (xi >= 0.f) && (xi < (float)Wl) && (yi >= 0.f) && (yi < (float)Hl);
                    if (valid && wgt != 0.f) {
                        int ix = (int)xi, iy = (int)yi;
                        acc += a * wgt * vlb[(size_t)(iy*Wl + ix)*D_];
                    }
                }
            }
        }
    }
    dout[gid] = acc;
}

// ---------------- launch ----------------
extern "C" void kernel_launch(void* const* d_in, const int* in_sizes, int n_in,
                              void* d_out, int out_size, void* d_ws, size_t ws_size,
                              hipStream_t stream) {
    (void)in_sizes; (void)n_in; (void)out_size; (void)ws_size;
    const float* h_in  = (const float*)d_in[0];
    const float* pos   = (const float*)d_in[1];
    const float* ehs   = (const float*)d_in[2];
    const float* refp  = (const float*)d_in[3];
    // d_in[4] = spatial_shapes (hardcoded)
    const float* wq    = (const float*)d_in[5];
    const float* bq    = (const float*)d_in[6];
    const float* wk    = (const float*)d_in[7];
    const float* bk    = (const float*)d_in[8];
    const float* wv    = (const float*)d_in[9];
    const float* bv    = (const float*)d_in[10];
    const float* wo    = (const float*)d_in[11];
    const float* bo    = (const float*)d_in[12];
    const float* ln1g  = (const float*)d_in[13];
    const float* ln1b  = (const float*)d_in[14];
    const float* w_off = (const float*)d_in[15];
    const float* b_off = (const float*)d_in[16];
    const float* w_aw  = (const float*)d_in[17];
    const float* b_aw  = (const float*)d_in[18];
    const float* w_val = (const float*)d_in[19];
    const float* b_val = (const float*)d_in[20];
    const float* w_out = (const float*)d_in[21];
    const float* b_out = (const float*)d_in[22];
    const float* ln2g  = (const float*)d_in[23];
    const float* ln2b  = (const float*)d_in[24];
    const float* w_fc1 = (const float*)d_in[25];
    const float* b_fc1 = (const float*)d_in[26];
    const float* w_fc2 = (const float*)d_in[27];
    const float* b_fc2 = (const float*)d_in[28];
    const float* ln3g  = (const float*)d_in[29];
    const float* ln3b  = (const float*)d_in[30];
    float* out = (float*)d_out;

    float* ws = (float*)d_ws;
    float* buf_hp   = ws + 0*(size_t)NB_;   // hp / hp2
    float* buf_q    = ws + 1*(size_t)NB_;   // q, later off (921600 < NB)
    float* buf_k    = ws + 2*(size_t)NB_;   // k, later aw  (460800 < NB)
    float* buf_v    = ws + 3*(size_t)NB_;   // v, later dout
    float* buf_sa   = ws + 4*(size_t)NB_;   // sa, later ca
    float* buf_tmp  = ws + 5*(size_t)NB_;   // sa2 / mlp
    float* buf_h1   = ws + 6*(size_t)NB_;
    float* buf_h2   = ws + 7*(size_t)NB_;
    float* buf_fc1  = ws + 8*(size_t)NB_;                 // 4,915,200 floats
    float* buf_val  = ws + 8*(size_t)NB_ + (size_t)ROWS_*FFN_;  // 34,406,400 floats

    const int n4 = NB_/4;
    dim3 blk(256);

    // hp = h + pos
    add_kernel<<<dim3((n4+255)/256), blk, 0, stream>>>(h_in, pos, buf_hp, n4);
    // q,k,v projections
    gemm_bias_act<<<dim3(D_/BN, ROWS_/BM), blk, 0, stream>>>(buf_hp, wq, bq, buf_q, ROWS_, D_, D_, 0);
    gemm_bias_act<<<dim3(D_/BN, ROWS_/BM), blk, 0, stream>>>(buf_hp, wk, bk, buf_k, ROWS_, D_, D_, 0);
    gemm_bias_act<<<dim3(D_/BN, ROWS_/BM), blk, 0, stream>>>(h_in,   wv, bv, buf_v, ROWS_, D_, D_, 0);
    // self attention (LDS-staged)
    self_attn_kernel<<<dim3(B_*NH_*3), blk, 0, stream>>>(buf_q, buf_k, buf_v, buf_sa);
    // output projection
    gemm_bias_act<<<dim3(D_/BN, ROWS_/BM), blk, 0, stream>>>(buf_sa, wo, bo, buf_tmp, ROWS_, D_, D_, 0);
    // LN1: h1 = LN(h + sa2)
    ln_add_kernel<<<dim3(ROWS_/4), blk, 0, stream>>>(h_in, buf_tmp, ln1g, ln1b, buf_h1);
    // hp2 = h1 + pos
    add_kernel<<<dim3((n4+255)/256), blk, 0, stream>>>(buf_h1, pos, buf_hp, n4);
    // value projection (big GEMM)
    gemm_bias_act<<<dim3(D_/BN, (B_*S_)/BM), blk, 0, stream>>>(ehs, w_val, b_val, buf_val, B_*S_, D_, D_, 0);
    // offsets + attention weights
    gemm_bias_act<<<dim3(192/BN, ROWS_/BM), blk, 0, stream>>>(buf_hp, w_off, b_off, buf_q, ROWS_, 192, D_, 0);
    gemm_bias_act<<<dim3((96+BN-1)/BN, ROWS_/BM), blk, 0, stream>>>(buf_hp, w_aw, b_aw, buf_k, ROWS_, 96, D_, 0);
    softmax12_kernel<<<dim3((ROWS_*NH_+255)/256), blk, 0, stream>>>(buf_k, ROWS_*NH_);
    // deformable sampling
    deform_kernel<<<dim3(NB_/256), blk, 0, stream>>>(buf_val, buf_q, buf_k, refp, buf_v);
    // ca projection
    gemm_bias_act<<<dim3(D_/BN, ROWS_/BM), blk, 0, stream>>>(buf_v, w_out, b_out, buf_sa, ROWS_, D_, D_, 0);
    // LN2
    ln_add_kernel<<<dim3(ROWS_/4), blk, 0, stream>>>(buf_h1, buf_sa, ln2g, ln2b, buf_h2);
    // FFN
    gemm_bias_act<<<dim3(FFN_/BN, ROWS_/BM), blk, 0, stream>>>(buf_h2, w_fc1, b_fc1, buf_fc1, ROWS_, FFN_, D_, 1);
    gemm_bias_act<<<dim3(D_/BN, ROWS_/BM), blk, 0, stream>>>(buf_fc1, w_fc2, b_fc2, buf_tmp, ROWS_, D_, FFN_, 0);
    // LN3 -> out
    ln_add_kernel<<<dim3(ROWS_/4), blk, 0, stream>>>(buf_h2, buf_tmp, ln3g, ln3b, out);
}

// Round 3
// 524.770 us; speedup vs baseline: 2.7750x; 1.4976x over previous
//
#include <hip/hip_runtime.h>
#include <hip/hip_bf16.h>
#include <math.h>

// ---------------- problem constants ----------------
#define B_   16
#define NQ_  300
#define D_   256
#define NH_  8
#define DH_  32
#define L_   3
#define P_   4
#define FFN_ 1024
#define S_   8400   // 80*80 + 40*40 + 20*20
#define ROWS_ (B_*NQ_)        // 4800
#define NB_   (ROWS_*D_)      // 1228800 floats per (B,NQ,D) buffer

typedef __attribute__((ext_vector_type(4))) unsigned short ushort4_t;
typedef __attribute__((ext_vector_type(8))) unsigned short ushort8_t;
typedef __attribute__((ext_vector_type(8))) short bf16x8;
typedef __attribute__((ext_vector_type(4))) float f32x4;

__device__ inline unsigned short f2b(float f) {
    __hip_bfloat16 h = __float2bfloat16(f);
    return __builtin_bit_cast(unsigned short, h);
}
__device__ inline float b2f(unsigned short u) {
    union { unsigned u; float f; } c; c.u = ((unsigned)u) << 16; return c.f;
}

// ---------------- elementwise add (float4) ----------------
__global__ __launch_bounds__(256) void add_kernel(const float* __restrict__ a,
                                                  const float* __restrict__ b,
                                                  float* __restrict__ o, int n4) {
    int i = blockIdx.x * 256 + threadIdx.x;
    if (i < n4) {
        float4 va = ((const float4*)a)[i];
        float4 vb = ((const float4*)b)[i];
        float4 vo = {va.x+vb.x, va.y+vb.y, va.z+vb.z, va.w+vb.w};
        ((float4*)o)[i] = vo;
    }
}

// ---------------- weight transpose+cast: W (KxN fp32) -> WT (NxK bf16) --------
// grid (N/32, K/32), block 256
__global__ __launch_bounds__(256) void wtrans_kernel(
    const float* __restrict__ w, unsigned short* __restrict__ wt, int K, int N)
{
    __shared__ unsigned short t[32][33];
    int tid = threadIdx.x;
    int tx = tid & 31, ty = tid >> 5;           // ty 0..7
    int n0 = blockIdx.x * 32, k0 = blockIdx.y * 32;
    #pragma unroll
    for (int i = 0; i < 4; ++i) {
        int k = k0 + ty + i*8;
        int n = n0 + tx;
        t[tx][ty + i*8] = f2b(w[(size_t)k*N + n]);
    }
    __syncthreads();
    #pragma unroll
    for (int i = 0; i < 4; ++i) {
        int n = n0 + ty + i*8;
        int k = k0 + tx;
        wt[(size_t)n*K + k] = t[ty + i*8][tx];
    }
}

// ---------------- bf16 MFMA GEMM: C = A(MxK fp32) @ W(KxN, given as WT NxK bf16) ----
// tile 128x128, 4 waves (2x2 of 64x64), K-step 32, mfma_f32_16x16x32_bf16
__global__ __launch_bounds__(256) void gemm_mfma(
    const float* __restrict__ A, const unsigned short* __restrict__ WT,
    const float* __restrict__ bias, float* __restrict__ C,
    int M, int N, int K, int relu)
{
    __shared__ unsigned short As[128][40];   // +8 pad: 80B rows, conflict-light b128 reads
    __shared__ unsigned short Bs[128][40];

    const int tid  = threadIdx.x;
    const int lane = tid & 63;
    const int w    = tid >> 6;
    const int wr   = w >> 1, wc = w & 1;
    const int m0   = blockIdx.y * 128;
    const int n0   = blockIdx.x * 128;

    const int fr = lane & 15;       // fragment row/col index
    const int fq = lane >> 4;       // k-block / row-quad index

    // staging coords: thread t covers (row = t>>1, k-seg = (t&1)*16 .. +15)
    const int srow = tid >> 1;
    const int sseg = (tid & 1) * 16;
    const int ga_row = m0 + srow;
    const int gb_row = n0 + srow;
    const bool a_ok = ga_row < M;
    const bool b_ok = gb_row < N;
    const float*          aptr = A  + (size_t)ga_row * K + sseg;
    const unsigned short* bptr = WT + (size_t)gb_row * K + sseg;

    f32x4 acc[4][4];
    #pragma unroll
    for (int m = 0; m < 4; ++m)
        #pragma unroll
        for (int n = 0; n < 4; ++n)
            acc[m][n] = (f32x4){0.f, 0.f, 0.f, 0.f};

    for (int k0 = 0; k0 < K; k0 += 32) {
        // ---- issue global loads to regs (before barrier) ----
        unsigned short abuf[16];
        if (a_ok) {
            const float* p = aptr + k0;
            #pragma unroll
            for (int j = 0; j < 4; ++j) {
                float4 v = *(const float4*)(p + j*4);
                abuf[j*4+0] = f2b(v.x); abuf[j*4+1] = f2b(v.y);
                abuf[j*4+2] = f2b(v.z); abuf[j*4+3] = f2b(v.w);
            }
        } else {
            #pragma unroll
            for (int j = 0; j < 16; ++j) abuf[j] = 0;
        }
        ushort8_t bv0, bv1;
        if (b_ok) {
            bv0 = *(const ushort8_t*)(bptr + k0);
            bv1 = *(const ushort8_t*)(bptr + k0 + 8);
        } else {
            #pragma unroll
            for (int j = 0; j < 8; ++j) { bv0[j] = 0; bv1[j] = 0; }
        }
        __syncthreads();   // previous iteration's LDS reads complete
        *(ushort8_t*)&As[srow][sseg]     = *(ushort8_t*)&abuf[0];
        *(ushort8_t*)&As[srow][sseg + 8] = *(ushort8_t*)&abuf[8];
        *(ushort8_t*)&Bs[srow][sseg]     = bv0;
        *(ushort8_t*)&Bs[srow][sseg + 8] = bv1;
        __syncthreads();
        // ---- fragments + MFMA ----
        bf16x8 af[4], bfr[4];
        #pragma unroll
        for (int m = 0; m < 4; ++m)
            af[m] = *(const bf16x8*)&As[wr*64 + m*16 + fr][fq * 8];
        #pragma unroll
        for (int n = 0; n < 4; ++n)
            bfr[n] = *(const bf16x8*)&Bs[wc*64 + n*16 + fr][fq * 8];
        #pragma unroll
        for (int m = 0; m < 4; ++m)
            #pragma unroll
            for (int n = 0; n < 4; ++n)
                acc[m][n] = __builtin_amdgcn_mfma_f32_16x16x32_bf16(
                    af[m], bfr[n], acc[m][n], 0, 0, 0);
    }

    // ---- epilogue: bias (+relu), guarded store ----
    #pragma unroll
    for (int n = 0; n < 4; ++n) {
        int col = n0 + wc*64 + n*16 + fr;
        if (col < N) {
            float bcol = bias[col];
            #pragma unroll
            for (int m = 0; m < 4; ++m) {
                int rbase = m0 + wr*64 + m*16 + fq*4;
                #pragma unroll
                for (int r = 0; r < 4; ++r) {
                    int row = rbase + r;
                    if (row < M) {
                        float vv = acc[m][n][r] + bcol;
                        if (relu) vv = fmaxf(vv, 0.f);
                        C[(size_t)row * N + col] = vv;
                    }
                }
            }
        }
    }
}

// ---------------- self attention: LDS-staged K/V (bf16), block per (b,h,third) ----
// grid.x = B*NH*3 = 384, block = 256 (4 waves, 25 queries each)
__global__ __launch_bounds__(256) void self_attn_kernel(
    const float* __restrict__ q, const float* __restrict__ k,
    const float* __restrict__ v, float* __restrict__ sa)
{
    __shared__ unsigned short k_lds[300][40];  // bf16, padded: 80B rows, 16B-aligned
    __shared__ unsigned short v_lds[300][32];  // bf16, 64B rows
    __shared__ float q_lds[4][32];
    __shared__ float p_lds[4][304];

    int bid = blockIdx.x;
    int part = bid % 3;            // query third: 0..2
    int bh = bid / 3;
    int h = bh & 7;
    int b = bh >> 3;
    int tid = threadIdx.x;
    int w = tid >> 6;
    int lane = tid & 63;

    // ---- stage K and V (fp32 global -> bf16 LDS), coalesced float4 loads ----
    const size_t base = (size_t)b*NQ_*D_ + h*DH_;
    for (int i = tid; i < 2400; i += 256) {
        int key = i >> 3, seg = i & 7;
        float4 kv = *(const float4*)(k + base + (size_t)key*D_ + seg*4);
        ushort4_t kb = { f2b(kv.x), f2b(kv.y), f2b(kv.z), f2b(kv.w) };
        *(ushort4_t*)&k_lds[key][seg*4] = kb;
        float4 vv = *(const float4*)(v + base + (size_t)key*D_ + seg*4);
        ushort4_t vb = { f2b(vv.x), f2b(vv.y), f2b(vv.z), f2b(vv.w) };
        *(ushort4_t*)&v_lds[key][seg*4] = vb;
    }
    __syncthreads();

    const float scale = 0.17677669529663687f;   // 1/sqrt(32)
    const int q0 = part * 100 + w * 25;

    for (int it = 0; it < 25; ++it) {
        int query = q0 + it;
        if (lane < 32)
            q_lds[w][lane] = q[base + (size_t)query*D_ + lane];
        float qreg[32];
        #pragma unroll
        for (int j = 0; j < 8; ++j) {
            float4 t = *(const float4*)&q_lds[w][j*4];
            qreg[j*4+0] = t.x; qreg[j*4+1] = t.y;
            qreg[j*4+2] = t.z; qreg[j*4+3] = t.w;
        }

        float s[5];
        float m = -1e30f;
        #pragma unroll
        for (int kk = 0; kk < 5; ++kk) {
            int key = kk*64 + lane;
            float sc = -1e30f;
            if (key < NQ_) {
                float acc = 0.f;
                #pragma unroll
                for (int d8 = 0; d8 < 4; ++d8) {
                    ushort8_t kv = *(const ushort8_t*)&k_lds[key][d8*8];
                    #pragma unroll
                    for (int j = 0; j < 8; ++j)
                        acc += qreg[d8*8+j] * b2f(kv[j]);
                }
                sc = acc * scale;
            }
            s[kk] = sc;
            m = fmaxf(m, sc);
        }
        #pragma unroll
        for (int off = 32; off; off >>= 1) m = fmaxf(m, __shfl_xor(m, off));
        float lsum = 0.f;
        #pragma unroll
        for (int kk = 0; kk < 5; ++kk) {
            int key = kk*64 + lane;
            if (key < NQ_) {
                float e = __expf(s[kk] - m);
                p_lds[w][key] = e;
                lsum += e;
            }
        }
        #pragma unroll
        for (int off = 32; off; off >>= 1) lsum += __shfl_xor(lsum, off);
        float inv = 1.0f / lsum;

        int dg = (lane & 15) * 2;
        int kg = lane >> 4;
        float acc0 = 0.f, acc1 = 0.f;
        for (int key = kg; key < NQ_; key += 4) {
            float p = p_lds[w][key];
            unsigned u = *(const unsigned*)&v_lds[key][dg];
            acc0 += p * b2f((unsigned short)(u & 0xffff));
            acc1 += p * b2f((unsigned short)(u >> 16));
        }
        acc0 += __shfl_xor(acc0, 16); acc0 += __shfl_xor(acc0, 32);
        acc1 += __shfl_xor(acc1, 16); acc1 += __shfl_xor(acc1, 32);
        if (lane < 16) {
            float2 o = { acc0 * inv, acc1 * inv };
            *(float2*)&sa[base + (size_t)query*D_ + dg] = o;
        }
    }
}

// ---------------- LayerNorm(x + y) ----------------
__global__ __launch_bounds__(256) void ln_add_kernel(
    const float* __restrict__ x, const float* __restrict__ y,
    const float* __restrict__ g, const float* __restrict__ bb,
    float* __restrict__ out)
{
    int w = threadIdx.x >> 6, lane = threadIdx.x & 63;
    int row = blockIdx.x*4 + w;
    const float* xr = x + (size_t)row*D_;
    const float* yr = y + (size_t)row*D_;
    float vals[4];
    float s = 0.f;
    #pragma unroll
    for (int i = 0; i < 4; i++) { vals[i] = xr[lane + 64*i] + yr[lane + 64*i]; s += vals[i]; }
    #pragma unroll
    for (int off = 32; off; off >>= 1) s += __shfl_xor(s, off);
    float mean = s * (1.0f/D_);
    float vs = 0.f;
    #pragma unroll
    for (int i = 0; i < 4; i++) { float dd = vals[i]-mean; vs += dd*dd; }
    #pragma unroll
    for (int off = 32; off; off >>= 1) vs += __shfl_xor(vs, off);
    float rstd = rsqrtf(vs*(1.0f/D_) + 1e-5f);
    #pragma unroll
    for (int i = 0; i < 4; i++) {
        int c = lane + 64*i;
        out[(size_t)row*D_ + c] = (vals[i]-mean)*rstd*g[c] + bb[c];
    }
}

// ---------------- softmax over 12 (L*P) per (b,q,h) row, in place -------------
__global__ __launch_bounds__(256) void softmax12_kernel(float* __restrict__ aw, int nrows)
{
    int r = blockIdx.x*256 + threadIdx.x;
    if (r >= nrows) return;
    float* p = aw + (size_t)r*12;
    float v[12];
    float m = -1e30f;
    #pragma unroll
    for (int i = 0; i < 12; i++) { v[i] = p[i]; m = fmaxf(m, v[i]); }
    float s = 0.f;
    #pragma unroll
    for (int i = 0; i < 12; i++) { v[i] = __expf(v[i]-m); s += v[i]; }
    float inv = 1.f/s;
    #pragma unroll
    for (int i = 0; i < 12; i++) p[i] = v[i]*inv;
}

// ---------------- deformable bilinear sampling ----------------
__global__ __launch_bounds__(256) void deform_kernel(
    const float* __restrict__ value, const float* __restrict__ off,
    const float* __restrict__ aw, const float* __restrict__ refp,
    float* __restrict__ dout)
{
    int gid = blockIdx.x*256 + threadIdx.x;
    int d = gid & 31;
    int h = (gid >> 5) & 7;
    int bq = gid >> 8;
    int qq = bq % NQ_;
    int b  = bq / NQ_;

    const int starts[3] = {0, 6400, 8000};
    const int Hs[3] = {80, 40, 20};

    const float* offp = off + ((size_t)(b*NQ_+qq)*NH_ + h)*(L_*P_*2);
    const float* awp  = aw  + ((size_t)(b*NQ_+qq)*NH_ + h)*(L_*P_);
    const float* refq = refp + (size_t)(b*NQ_+qq)*(L_*2);
    const float* vb   = value + (size_t)b*S_*D_ + h*DH_ + d;

    float acc = 0.f;
    #pragma unroll
    for (int l = 0; l < L_; l++) {
        int Hl = Hs[l], Wl = Hs[l];
        float rx = refq[l*2+0], ry = refq[l*2+1];
        const float* vlb = vb + (size_t)starts[l]*D_;
        #pragma unroll
        for (int p = 0; p < P_; p++) {
            float ox = offp[(l*P_+p)*2+0], oy = offp[(l*P_+p)*2+1];
            float a  = awp[l*P_+p];
            float x = (rx + ox/(float)Wl)*(float)Wl - 0.5f;
            float y = (ry + oy/(float)Hl)*(float)Hl - 0.5f;
            float x0 = floorf(x), y0 = floorf(y);
            #pragma unroll
            for (int dy = 0; dy < 2; dy++) {
                #pragma unroll
                for (int dx = 0; dx < 2; dx++) {
                    float xi = x0 + dx, yi = y0 + dy;
                    float wgt = (1.f - fabsf(x-xi))*(1.f - fabsf(y-yi));
                    bool valid = (xi >= 0.f) && (xi < (float)Wl) && (yi >= 0.f) && (yi < (float)Hl);
                    if (valid && wgt != 0.f) {
                        int ix = (int)xi, iy = (int)yi;
                        acc += a * wgt * vlb[(size_t)(iy*Wl + ix)*D_];
                    }
                }
            }
        }
    }
    dout[gid] = acc;
}

// ---------------- launch ----------------
extern "C" void kernel_launch(void* const* d_in, const int* in_sizes, int n_in,
                              void* d_out, int out_size, void* d_ws, size_t ws_size,
                              hipStream_t stream) {
    (void)in_sizes; (void)n_in; (void)out_size; (void)ws_size;
    const float* h_in  = (const float*)d_in[0];
    const float* pos   = (const float*)d_in[1];
    const float* ehs   = (const float*)d_in[2];
    const float* refp  = (const float*)d_in[3];
    // d_in[4] = spatial_shapes (hardcoded)
    const float* wq    = (const float*)d_in[5];
    const float* bq    = (const float*)d_in[6];
    const float* wk    = (const float*)d_in[7];
    const float* bk    = (const float*)d_in[8];
    const float* wv    = (const float*)d_in[9];
    const float* bv    = (const float*)d_in[10];
    const float* wo    = (const float*)d_in[11];
    const float* bo    = (const float*)d_in[12];
    const float* ln1g  = (const float*)d_in[13];
    const float* ln1b  = (const float*)d_in[14];
    const float* w_off = (const float*)d_in[15];
    const float* b_off = (const float*)d_in[16];
    const float* w_aw  = (const float*)d_in[17];
    const float* b_aw  = (const float*)d_in[18];
    const float* w_val = (const float*)d_in[19];
    const float* b_val = (const float*)d_in[20];
    const float* w_out = (const float*)d_in[21];
    const float* b_out = (const float*)d_in[22];
    const float* ln2g  = (const float*)d_in[23];
    const float* ln2b  = (const float*)d_in[24];
    const float* w_fc1 = (const float*)d_in[25];
    const float* b_fc1 = (const float*)d_in[26];
    const float* w_fc2 = (const float*)d_in[27];
    const float* b_fc2 = (const float*)d_in[28];
    const float* ln3g  = (const float*)d_in[29];
    const float* ln3b  = (const float*)d_in[30];
    float* out = (float*)d_out;

    float* ws = (float*)d_ws;
    float* buf_hp   = ws + 0*(size_t)NB_;   // hp / hp2
    float* buf_q    = ws + 1*(size_t)NB_;   // q, later off (921600 < NB)
    float* buf_k    = ws + 2*(size_t)NB_;   // k, later aw  (460800 < NB)
    float* buf_v    = ws + 3*(size_t)NB_;   // v, later dout
    float* buf_sa   = ws + 4*(size_t)NB_;   // sa, later ca
    float* buf_tmp  = ws + 5*(size_t)NB_;   // sa2 / mlp
    float* buf_h1   = ws + 6*(size_t)NB_;
    float* buf_h2   = ws + 7*(size_t)NB_;
    float* buf_fc1  = ws + 8*(size_t)NB_;                       // 4,915,200 floats
    float* buf_val  = ws + 8*(size_t)NB_ + (size_t)ROWS_*FFN_;  // 34,406,400 floats

    // bf16 transposed weights region (ushort), after buf_val
    unsigned short* wtb = (unsigned short*)(ws + 8*(size_t)NB_ + (size_t)ROWS_*FFN_ + (size_t)B_*S_*D_);
    unsigned short* wtq   = wtb;                 // 256x256
    unsigned short* wtk   = wtq   + 65536;
    unsigned short* wtv   = wtk   + 65536;
    unsigned short* wto   = wtv   + 65536;
    unsigned short* wtval = wto   + 65536;
    unsigned short* wtout = wtval + 65536;
    unsigned short* wtoff = wtout + 65536;       // 192x256
    unsigned short* wtaw  = wtoff + 49152;       // 96x256
    unsigned short* wtfc1 = wtaw  + 24576;       // 1024x256
    unsigned short* wtfc2 = wtfc1 + 262144;      // 256x1024

    const int n4 = NB_/4;
    dim3 blk(256);

    // ---- weight prep (transpose + bf16 cast) ----
    wtrans_kernel<<<dim3(8, 8),  blk, 0, stream>>>(wq,    wtq,   D_, D_);
    wtrans_kernel<<<dim3(8, 8),  blk, 0, stream>>>(wk,    wtk,   D_, D_);
    wtrans_kernel<<<dim3(8, 8),  blk, 0, stream>>>(wv,    wtv,   D_, D_);
    wtrans_kernel<<<dim3(8, 8),  blk, 0, stream>>>(wo,    wto,   D_, D_);
    wtrans_kernel<<<dim3(8, 8),  blk, 0, stream>>>(w_val, wtval, D_, D_);
    wtrans_kernel<<<dim3(8, 8),  blk, 0, stream>>>(w_out, wtout, D_, D_);
    wtrans_kernel<<<dim3(6, 8),  blk, 0, stream>>>(w_off, wtoff, D_, 192);
    wtrans_kernel<<<dim3(3, 8),  blk, 0, stream>>>(w_aw,  wtaw,  D_, 96);
    wtrans_kernel<<<dim3(32, 8), blk, 0, stream>>>(w_fc1, wtfc1, D_, FFN_);
    wtrans_kernel<<<dim3(8, 32), blk, 0, stream>>>(w_fc2, wtfc2, FFN_, D_);

    // hp = h + pos
    add_kernel<<<dim3((n4+255)/256), blk, 0, stream>>>(h_in, pos, buf_hp, n4);
    // q,k,v projections (MFMA)
    gemm_mfma<<<dim3(2, 38), blk, 0, stream>>>(buf_hp, wtq, bq, buf_q, ROWS_, D_, D_, 0);
    gemm_mfma<<<dim3(2, 38), blk, 0, stream>>>(buf_hp, wtk, bk, buf_k, ROWS_, D_, D_, 0);
    gemm_mfma<<<dim3(2, 38), blk, 0, stream>>>(h_in,   wtv, bv, buf_v, ROWS_, D_, D_, 0);
    // self attention (LDS-staged)
    self_attn_kernel<<<dim3(B_*NH_*3), blk, 0, stream>>>(buf_q, buf_k, buf_v, buf_sa);
    // output projection
    gemm_mfma<<<dim3(2, 38), blk, 0, stream>>>(buf_sa, wto, bo, buf_tmp, ROWS_, D_, D_, 0);
    // LN1: h1 = LN(h + sa2)
    ln_add_kernel<<<dim3(ROWS_/4), blk, 0, stream>>>(h_in, buf_tmp, ln1g, ln1b, buf_h1);
    // hp2 = h1 + pos
    add_kernel<<<dim3((n4+255)/256), blk, 0, stream>>>(buf_h1, pos, buf_hp, n4);
    // value projection (big GEMM): M = 134400 = 1050*128 exact
    gemm_mfma<<<dim3(2, 1050), blk, 0, stream>>>(ehs, wtval, b_val, buf_val, B_*S_, D_, D_, 0);
    // offsets + attention weights
    gemm_mfma<<<dim3(2, 38), blk, 0, stream>>>(buf_hp, wtoff, b_off, buf_q, ROWS_, 192, D_, 0);
    gemm_mfma<<<dim3(1, 38), blk, 0, stream>>>(buf_hp, wtaw,  b_aw,  buf_k, ROWS_, 96,  D_, 0);
    softmax12_kernel<<<dim3((ROWS_*NH_+255)/256), blk, 0, stream>>>(buf_k, ROWS_*NH_);
    // deformable sampling
    deform_kernel<<<dim3(NB_/256), blk, 0, stream>>>(buf_val, buf_q, buf_k, refp, buf_v);
    // ca projection
    gemm_mfma<<<dim3(2, 38), blk, 0, stream>>>(buf_v, wtout, b_out, buf_sa, ROWS_, D_, D_, 0);
    // LN2
    ln_add_kernel<<<dim3(ROWS_/4), blk, 0, stream>>>(buf_h1, buf_sa, ln2g, ln2b, buf_h2);
    // FFN
    gemm_mfma<<<dim3(8, 38), blk, 0, stream>>>(buf_h2, wtfc1, b_fc1, buf_fc1, ROWS_, FFN_, D_, 1);
    gemm_mfma<<<dim3(2, 38), blk, 0, stream>>>(buf_fc1, wtfc2, b_fc2, buf_tmp, ROWS_, D_, FFN_, 0);
    // LN3 -> out
    ln_add_kernel<<<dim3(ROWS_/4), blk, 0, stream>>>(buf_h2, buf_tmp, ln3g, ln3b, out);
}

// Round 4
// 417.793 us; speedup vs baseline: 3.4855x; 1.2561x over previous
//
#include <hip/hip_runtime.h>
#include <hip/hip_bf16.h>
#include <math.h>

// ---------------- problem constants ----------------
#define B_   16
#define NQ_  300
#define D_   256
#define NH_  8
#define DH_  32
#define L_   3
#define P_   4
#define FFN_ 1024
#define S_   8400   // 80*80 + 40*40 + 20*20
#define ROWS_ (B_*NQ_)        // 4800
#define NB_   (ROWS_*D_)      // 1228800 floats per (B,NQ,D) buffer

typedef __attribute__((ext_vector_type(4))) unsigned short ushort4_t;
typedef __attribute__((ext_vector_type(8))) unsigned short ushort8_t;
typedef __attribute__((ext_vector_type(8))) short bf16x8;
typedef __attribute__((ext_vector_type(4))) float f32x4;

__device__ inline unsigned short f2b(float f) {
    __hip_bfloat16 h = __float2bfloat16(f);
    return __builtin_bit_cast(unsigned short, h);
}
__device__ inline float b2f(unsigned short u) {
    union { unsigned u; float f; } c; c.u = ((unsigned)u) << 16; return c.f;
}

// ---------------- elementwise add (float4) ----------------
__global__ __launch_bounds__(256) void add_kernel(const float* __restrict__ a,
                                                  const float* __restrict__ b,
                                                  float* __restrict__ o, int n4) {
    int i = blockIdx.x * 256 + threadIdx.x;
    if (i < n4) {
        float4 va = ((const float4*)a)[i];
        float4 vb = ((const float4*)b)[i];
        float4 vo = {va.x+vb.x, va.y+vb.y, va.z+vb.z, va.w+vb.w};
        ((float4*)o)[i] = vo;
    }
}

// ---------------- weight transpose+cast: W (KxN fp32) -> WT (NxK bf16) --------
__global__ __launch_bounds__(256) void wtrans_kernel(
    const float* __restrict__ w, unsigned short* __restrict__ wt, int K, int N)
{
    __shared__ unsigned short t[32][33];
    int tid = threadIdx.x;
    int tx = tid & 31, ty = tid >> 5;           // ty 0..7
    int n0 = blockIdx.x * 32, k0 = blockIdx.y * 32;
    #pragma unroll
    for (int i = 0; i < 4; ++i) {
        int k = k0 + ty + i*8;
        int n = n0 + tx;
        t[tx][ty + i*8] = f2b(w[(size_t)k*N + n]);
    }
    __syncthreads();
    #pragma unroll
    for (int i = 0; i < 4; ++i) {
        int n = n0 + ty + i*8;
        int k = k0 + tx;
        wt[(size_t)n*K + k] = t[ty + i*8][tx];
    }
}

// ---------------- bf16 MFMA GEMM: C = A(MxK fp32) @ W(KxN, given as WT NxK bf16) ----
// tile 128x128, 4 waves (2x2 of 64x64), K-step 32, mfma_f32_16x16x32_bf16
__global__ __launch_bounds__(256) void gemm_mfma(
    const float* __restrict__ A, const unsigned short* __restrict__ WT,
    const float* __restrict__ bias, float* __restrict__ C,
    int M, int N, int K, int relu)
{
    __shared__ unsigned short As[128][40];
    __shared__ unsigned short Bs[128][40];

    const int tid  = threadIdx.x;
    const int lane = tid & 63;
    const int w    = tid >> 6;
    const int wr   = w >> 1, wc = w & 1;
    const int m0   = blockIdx.y * 128;
    const int n0   = blockIdx.x * 128;

    const int fr = lane & 15;
    const int fq = lane >> 4;

    const int srow = tid >> 1;
    const int sseg = (tid & 1) * 16;
    const int ga_row = m0 + srow;
    const int gb_row = n0 + srow;
    const bool a_ok = ga_row < M;
    const bool b_ok = gb_row < N;
    const float*          aptr = A  + (size_t)ga_row * K + sseg;
    const unsigned short* bptr = WT + (size_t)gb_row * K + sseg;

    f32x4 acc[4][4];
    #pragma unroll
    for (int m = 0; m < 4; ++m)
        #pragma unroll
        for (int n = 0; n < 4; ++n)
            acc[m][n] = (f32x4){0.f, 0.f, 0.f, 0.f};

    for (int k0 = 0; k0 < K; k0 += 32) {
        unsigned short abuf[16];
        if (a_ok) {
            const float* p = aptr + k0;
            #pragma unroll
            for (int j = 0; j < 4; ++j) {
                float4 v = *(const float4*)(p + j*4);
                abuf[j*4+0] = f2b(v.x); abuf[j*4+1] = f2b(v.y);
                abuf[j*4+2] = f2b(v.z); abuf[j*4+3] = f2b(v.w);
            }
        } else {
            #pragma unroll
            for (int j = 0; j < 16; ++j) abuf[j] = 0;
        }
        ushort8_t bv0, bv1;
        if (b_ok) {
            bv0 = *(const ushort8_t*)(bptr + k0);
            bv1 = *(const ushort8_t*)(bptr + k0 + 8);
        } else {
            #pragma unroll
            for (int j = 0; j < 8; ++j) { bv0[j] = 0; bv1[j] = 0; }
        }
        __syncthreads();
        *(ushort8_t*)&As[srow][sseg]     = *(ushort8_t*)&abuf[0];
        *(ushort8_t*)&As[srow][sseg + 8] = *(ushort8_t*)&abuf[8];
        *(ushort8_t*)&Bs[srow][sseg]     = bv0;
        *(ushort8_t*)&Bs[srow][sseg + 8] = bv1;
        __syncthreads();
        bf16x8 af[4], bfr[4];
        #pragma unroll
        for (int m = 0; m < 4; ++m)
            af[m] = *(const bf16x8*)&As[wr*64 + m*16 + fr][fq * 8];
        #pragma unroll
        for (int n = 0; n < 4; ++n)
            bfr[n] = *(const bf16x8*)&Bs[wc*64 + n*16 + fr][fq * 8];
        #pragma unroll
        for (int m = 0; m < 4; ++m)
            #pragma unroll
            for (int n = 0; n < 4; ++n)
                acc[m][n] = __builtin_amdgcn_mfma_f32_16x16x32_bf16(
                    af[m], bfr[n], acc[m][n], 0, 0, 0);
    }

    #pragma unroll
    for (int n = 0; n < 4; ++n) {
        int col = n0 + wc*64 + n*16 + fr;
        if (col < N) {
            float bcol = bias[col];
            #pragma unroll
            for (int m = 0; m < 4; ++m) {
                int rbase = m0 + wr*64 + m*16 + fq*4;
                #pragma unroll
                for (int r = 0; r < 4; ++r) {
                    int row = rbase + r;
                    if (row < M) {
                        float vv = acc[m][n][r] + bcol;
                        if (relu) vv = fmaxf(vv, 0.f);
                        C[(size_t)row * N + col] = vv;
                    }
                }
            }
        }
    }
}

// ---------------- self attention via MFMA ----------------
// grid.x = B*NH*5 = 640; block 256 = 4 waves; each wave: 16 queries.
// Swapped QK^T: mfma(K_frag, Q_frag) -> S^T tile (row=key, col=query).
// Softmax per query column: 2x shfl_xor(16,32). P packed to per-wave LDS.
// PV: mfma(P_frag, Vt_frag) -> out (row=query, col=d).
__global__ __launch_bounds__(256) void self_attn_kernel(
    const float* __restrict__ q, const float* __restrict__ k,
    const float* __restrict__ v, float* __restrict__ sa)
{
    __shared__ unsigned short k_sw[304*32];      // K bf16, 16B-unit XOR swizzled
    __shared__ unsigned short vt[32][312];       // V^T bf16: [d][key]
    __shared__ unsigned short p_all[4][16][312]; // per-wave P: [q_local][key]

    const int bid  = blockIdx.x;
    const int part = bid % 5;
    const int bh   = bid / 5;
    const int h    = bh & 7;
    const int b    = bh >> 3;
    const int tid  = threadIdx.x;
    const int lane = tid & 63;
    const int w    = tid >> 6;
    const int g    = lane >> 4;   // 0..3
    const int fr   = lane & 15;

    const size_t base = (size_t)b*NQ_*D_ + h*DH_;

    // ---- stage K: rows 0..303 (zero-pad >=300), swizzle 16B unit u^=(r>>1)&3 ----
    for (int i = tid; i < 1216; i += 256) {
        int r = i >> 2, u = i & 3;
        ushort8_t kb;
        if (r < NQ_) {
            const float* p8 = k + base + (size_t)r*D_ + u*8;
            float4 a0 = *(const float4*)p8;
            float4 a1 = *(const float4*)(p8 + 4);
            kb[0]=f2b(a0.x); kb[1]=f2b(a0.y); kb[2]=f2b(a0.z); kb[3]=f2b(a0.w);
            kb[4]=f2b(a1.x); kb[5]=f2b(a1.y); kb[6]=f2b(a1.z); kb[7]=f2b(a1.w);
        } else {
            #pragma unroll
            for (int j = 0; j < 8; ++j) kb[j] = 0;
        }
        int su = u ^ ((r >> 1) & 3);
        *(ushort8_t*)&k_sw[r*32 + su*8] = kb;
    }
    // ---- stage V transposed: vt[d][key] ----
    for (int i = tid; i < 1216; i += 256) {
        int kk = i >> 2, u = i & 3;
        if (kk < NQ_) {
            const float* p8 = v + base + (size_t)kk*D_ + u*8;
            float4 a0 = *(const float4*)p8;
            float4 a1 = *(const float4*)(p8 + 4);
            float f[8] = {a0.x,a0.y,a0.z,a0.w,a1.x,a1.y,a1.z,a1.w};
            #pragma unroll
            for (int j = 0; j < 8; ++j) vt[u*8 + j][kk] = f2b(f[j]);
        } else {
            #pragma unroll
            for (int j = 0; j < 8; ++j) vt[u*8 + j][kk] = 0;
        }
    }
    __syncthreads();

    // ---- Q fragment: q_local = fr, k-range = g*8..g*8+7, pre-scaled ----
    const int q0 = part*64 + w*16;
    const int qi = q0 + fr;
    bf16x8 qf;
    if (qi < NQ_) {
        const float scale = 0.17677669529663687f;   // 1/sqrt(32)
        const float* p8 = q + base + (size_t)qi*D_ + g*8;
        float4 a0 = *(const float4*)p8;
        float4 a1 = *(const float4*)(p8 + 4);
        qf[0]=(short)f2b(a0.x*scale); qf[1]=(short)f2b(a0.y*scale);
        qf[2]=(short)f2b(a0.z*scale); qf[3]=(short)f2b(a0.w*scale);
        qf[4]=(short)f2b(a1.x*scale); qf[5]=(short)f2b(a1.y*scale);
        qf[6]=(short)f2b(a1.z*scale); qf[7]=(short)f2b(a1.w*scale);
    } else {
        #pragma unroll
        for (int j = 0; j < 8; ++j) qf[j] = 0;
    }

    // ---- QK^T: 19 key-tiles; S^T tile: row=key(g*4+r), col=query(fr) ----
    const int ksw_u = g ^ ((fr >> 1) & 3);   // (row>>1)&3 == (fr>>1)&3 since tile*16 ≡ 0 mod 4-pairs
    f32x4 acc[19];
    #pragma unroll
    for (int t = 0; t < 19; ++t) acc[t] = (f32x4){0.f,0.f,0.f,0.f};
    #pragma unroll
    for (int t = 0; t < 19; ++t) {
        int row = t*16 + fr;
        bf16x8 kf = *(const bf16x8*)&k_sw[row*32 + ksw_u*8];
        acc[t] = __builtin_amdgcn_mfma_f32_16x16x32_bf16(kf, qf, acc[t], 0, 0, 0);
    }
    // mask invalid keys 300..303 (tile 18, rows 12..15 -> g==3)
    if (g == 3) acc[18] = (f32x4){-1e30f, -1e30f, -1e30f, -1e30f};

    // ---- softmax per query column ----
    float m = -1e30f;
    #pragma unroll
    for (int t = 0; t < 19; ++t) {
        #pragma unroll
        for (int r = 0; r < 4; ++r) m = fmaxf(m, acc[t][r]);
    }
    m = fmaxf(m, __shfl_xor(m, 16));
    m = fmaxf(m, __shfl_xor(m, 32));
    float lsum = 0.f;
    #pragma unroll
    for (int t = 0; t < 19; ++t) {
        #pragma unroll
        for (int r = 0; r < 4; ++r) {
            float e = __expf(acc[t][r] - m);
            acc[t][r] = e;
            lsum += e;
        }
    }
    lsum += __shfl_xor(lsum, 16);
    lsum += __shfl_xor(lsum, 32);
    float inv = 1.0f / lsum;

    // ---- P -> LDS (bf16, normalized). key of acc[t][r] = t*16 + g*4 + r ----
    #pragma unroll
    for (int t = 0; t < 19; ++t) {
        ushort4_t pw = { f2b(acc[t][0]*inv), f2b(acc[t][1]*inv),
                         f2b(acc[t][2]*inv), f2b(acc[t][3]*inv) };
        *(ushort4_t*)&p_all[w][fr][t*16 + g*4] = pw;
    }

    // ---- PV: out[16 q][32 d]; k-steps of 32 over 304 keys ----
    f32x4 o0 = (f32x4){0.f,0.f,0.f,0.f};
    f32x4 o1 = (f32x4){0.f,0.f,0.f,0.f};
    #pragma unroll
    for (int ks = 0; ks < 10; ++ks) {
        int kb = ks*32 + g*8;
        bf16x8 pf, vf0, vf1;
        if (kb < 304) {
            pf  = *(const bf16x8*)&p_all[w][fr][kb];
            vf0 = *(const bf16x8*)&vt[fr][kb];
            vf1 = *(const bf16x8*)&vt[16 + fr][kb];
        } else {
            #pragma unroll
            for (int j = 0; j < 8; ++j) { pf[j] = 0; vf0[j] = 0; vf1[j] = 0; }
        }
        o0 = __builtin_amdgcn_mfma_f32_16x16x32_bf16(pf, vf0, o0, 0, 0, 0);
        o1 = __builtin_amdgcn_mfma_f32_16x16x32_bf16(pf, vf1, o1, 0, 0, 0);
    }

    // ---- store: row=q_local=g*4+r, col=d=nd*16+fr ----
    #pragma unroll
    for (int r = 0; r < 4; ++r) {
        int qo = q0 + g*4 + r;
        if (qo < NQ_) {
            sa[base + (size_t)qo*D_ + fr]      = o0[r];
            sa[base + (size_t)qo*D_ + 16 + fr] = o1[r];
        }
    }
}

// ---------------- LayerNorm(x + y) ----------------
__global__ __launch_bounds__(256) void ln_add_kernel(
    const float* __restrict__ x, const float* __restrict__ y,
    const float* __restrict__ g, const float* __restrict__ bb,
    float* __restrict__ out)
{
    int w = threadIdx.x >> 6, lane = threadIdx.x & 63;
    int row = blockIdx.x*4 + w;
    const float* xr = x + (size_t)row*D_;
    const float* yr = y + (size_t)row*D_;
    float vals[4];
    float s = 0.f;
    #pragma unroll
    for (int i = 0; i < 4; i++) { vals[i] = xr[lane + 64*i] + yr[lane + 64*i]; s += vals[i]; }
    #pragma unroll
    for (int off = 32; off; off >>= 1) s += __shfl_xor(s, off);
    float mean = s * (1.0f/D_);
    float vs = 0.f;
    #pragma unroll
    for (int i = 0; i < 4; i++) { float dd = vals[i]-mean; vs += dd*dd; }
    #pragma unroll
    for (int off = 32; off; off >>= 1) vs += __shfl_xor(vs, off);
    float rstd = rsqrtf(vs*(1.0f/D_) + 1e-5f);
    #pragma unroll
    for (int i = 0; i < 4; i++) {
        int c = lane + 64*i;
        out[(size_t)row*D_ + c] = (vals[i]-mean)*rstd*g[c] + bb[c];
    }
}

// ---------------- softmax over 12 (L*P) per (b,q,h) row, in place -------------
__global__ __launch_bounds__(256) void softmax12_kernel(float* __restrict__ aw, int nrows)
{
    int r = blockIdx.x*256 + threadIdx.x;
    if (r >= nrows) return;
    float* p = aw + (size_t)r*12;
    float v[12];
    float m = -1e30f;
    #pragma unroll
    for (int i = 0; i < 12; i++) { v[i] = p[i]; m = fmaxf(m, v[i]); }
    float s = 0.f;
    #pragma unroll
    for (int i = 0; i < 12; i++) { v[i] = __expf(v[i]-m); s += v[i]; }
    float inv = 1.f/s;
    #pragma unroll
    for (int i = 0; i < 12; i++) p[i] = v[i]*inv;
}

// ---------------- deformable bilinear sampling ----------------
__global__ __launch_bounds__(256) void deform_kernel(
    const float* __restrict__ value, const float* __restrict__ off,
    const float* __restrict__ aw, const float* __restrict__ refp,
    float* __restrict__ dout)
{
    int gid = blockIdx.x*256 + threadIdx.x;
    int d = gid & 31;
    int h = (gid >> 5) & 7;
    int bq = gid >> 8;
    int qq = bq % NQ_;
    int b  = bq / NQ_;

    const int starts[3] = {0, 6400, 8000};
    const int Hs[3] = {80, 40, 20};

    const float* offp = off + ((size_t)(b*NQ_+qq)*NH_ + h)*(L_*P_*2);
    const float* awp  = aw  + ((size_t)(b*NQ_+qq)*NH_ + h)*(L_*P_);
    const float* refq = refp + (size_t)(b*NQ_+qq)*(L_*2);
    const float* vb   = value + (size_t)b*S_*D_ + h*DH_ + d;

    float acc = 0.f;
    #pragma unroll
    for (int l = 0; l < L_; l++) {
        int Hl = Hs[l], Wl = Hs[l];
        float rx = refq[l*2+0], ry = refq[l*2+1];
        const float* vlb = vb + (size_t)starts[l]*D_;
        #pragma unroll
        for (int p = 0; p < P_; p++) {
            float ox = offp[(l*P_+p)*2+0], oy = offp[(l*P_+p)*2+1];
            float a  = awp[l*P_+p];
            float x = (rx + ox/(float)Wl)*(float)Wl - 0.5f;
            float y = (ry + oy/(float)Hl)*(float)Hl - 0.5f;
            float x0 = floorf(x), y0 = floorf(y);
            #pragma unroll
            for (int dy = 0; dy < 2; dy++) {
                #pragma unroll
                for (int dx = 0; dx < 2; dx++) {
                    float xi = x0 + dx, yi = y0 + dy;
                    float wgt = (1.f - fabsf(x-xi))*(1.f - fabsf(y-yi));
                    bool valid = (xi >= 0.f) && (xi < (float)Wl) && (yi >= 0.f) && (yi < (float)Hl);
                    if (valid && wgt != 0.f) {
                        int ix = (int)xi, iy = (int)yi;
                        acc += a * wgt * vlb[(size_t)(iy*Wl + ix)*D_];
                    }
                }
            }
        }
    }
    dout[gid] = acc;
}

// ---------------- launch ----------------
extern "C" void kernel_launch(void* const* d_in, const int* in_sizes, int n_in,
                              void* d_out, int out_size, void* d_ws, size_t ws_size,
                              hipStream_t stream) {
    (void)in_sizes; (void)n_in; (void)out_size; (void)ws_size;
    const float* h_in  = (const float*)d_in[0];
    const float* pos   = (const float*)d_in[1];
    const float* ehs   = (const float*)d_in[2];
    const float* refp  = (const float*)d_in[3];
    // d_in[4] = spatial_shapes (hardcoded)
    const float* wq    = (const float*)d_in[5];
    const float* bq    = (const float*)d_in[6];
    const float* wk    = (const float*)d_in[7];
    const float* bk    = (const float*)d_in[8];
    const float* wv    = (const float*)d_in[9];
    const float* bv    = (const float*)d_in[10];
    const float* wo    = (const float*)d_in[11];
    const float* bo    = (const float*)d_in[12];
    const float* ln1g  = (const float*)d_in[13];
    const float* ln1b  = (const float*)d_in[14];
    const float* w_off = (const float*)d_in[15];
    const float* b_off = (const float*)d_in[16];
    const float* w_aw  = (const float*)d_in[17];
    const float* b_aw  = (const float*)d_in[18];
    const float* w_val = (const float*)d_in[19];
    const float* b_val = (const float*)d_in[20];
    const float* w_out = (const float*)d_in[21];
    const float* b_out = (const float*)d_in[22];
    const float* ln2g  = (const float*)d_in[23];
    const float* ln2b  = (const float*)d_in[24];
    const float* w_fc1 = (const float*)d_in[25];
    const float* b_fc1 = (const float*)d_in[26];
    const float* w_fc2 = (const float*)d_in[27];
    const float* b_fc2 = (const float*)d_in[28];
    const float* ln3g  = (const float*)d_in[29];
    const float* ln3b  = (const float*)d_in[30];
    float* out = (float*)d_out;

    float* ws = (float*)d_ws;
    float* buf_hp   = ws + 0*(size_t)NB_;   // hp / hp2
    float* buf_q    = ws + 1*(size_t)NB_;   // q, later off (921600 < NB)
    float* buf_k    = ws + 2*(size_t)NB_;   // k, later aw  (460800 < NB)
    float* buf_v    = ws + 3*(size_t)NB_;   // v, later dout
    float* buf_sa   = ws + 4*(size_t)NB_;   // sa, later ca
    float* buf_tmp  = ws + 5*(size_t)NB_;   // sa2 / mlp
    float* buf_h1   = ws + 6*(size_t)NB_;
    float* buf_h2   = ws + 7*(size_t)NB_;
    float* buf_fc1  = ws + 8*(size_t)NB_;                       // 4,915,200 floats
    float* buf_val  = ws + 8*(size_t)NB_ + (size_t)ROWS_*FFN_;  // 34,406,400 floats

    // bf16 transposed weights region (ushort), after buf_val
    unsigned short* wtb = (unsigned short*)(ws + 8*(size_t)NB_ + (size_t)ROWS_*FFN_ + (size_t)B_*S_*D_);
    unsigned short* wtq   = wtb;                 // 256x256
    unsigned short* wtk   = wtq   + 65536;
    unsigned short* wtv   = wtk   + 65536;
    unsigned short* wto   = wtv   + 65536;
    unsigned short* wtval = wto   + 65536;
    unsigned short* wtout = wtval + 65536;
    unsigned short* wtoff = wtout + 65536;       // 192x256
    unsigned short* wtaw  = wtoff + 49152;       // 96x256
    unsigned short* wtfc1 = wtaw  + 24576;       // 1024x256
    unsigned short* wtfc2 = wtfc1 + 262144;      // 256x1024

    const int n4 = NB_/4;
    dim3 blk(256);

    // ---- weight prep (transpose + bf16 cast) ----
    wtrans_kernel<<<dim3(8, 8),  blk, 0, stream>>>(wq,    wtq,   D_, D_);
    wtrans_kernel<<<dim3(8, 8),  blk, 0, stream>>>(wk,    wtk,   D_, D_);
    wtrans_kernel<<<dim3(8, 8),  blk, 0, stream>>>(wv,    wtv,   D_, D_);
    wtrans_kernel<<<dim3(8, 8),  blk, 0, stream>>>(wo,    wto,   D_, D_);
    wtrans_kernel<<<dim3(8, 8),  blk, 0, stream>>>(w_val, wtval, D_, D_);
    wtrans_kernel<<<dim3(8, 8),  blk, 0, stream>>>(w_out, wtout, D_, D_);
    wtrans_kernel<<<dim3(6, 8),  blk, 0, stream>>>(w_off, wtoff, D_, 192);
    wtrans_kernel<<<dim3(3, 8),  blk, 0, stream>>>(w_aw,  wtaw,  D_, 96);
    wtrans_kernel<<<dim3(32, 8), blk, 0, stream>>>(w_fc1, wtfc1, D_, FFN_);
    wtrans_kernel<<<dim3(8, 32), blk, 0, stream>>>(w_fc2, wtfc2, FFN_, D_);

    // hp = h + pos
    add_kernel<<<dim3((n4+255)/256), blk, 0, stream>>>(h_in, pos, buf_hp, n4);
    // q,k,v projections (MFMA)
    gemm_mfma<<<dim3(2, 38), blk, 0, stream>>>(buf_hp, wtq, bq, buf_q, ROWS_, D_, D_, 0);
    gemm_mfma<<<dim3(2, 38), blk, 0, stream>>>(buf_hp, wtk, bk, buf_k, ROWS_, D_, D_, 0);
    gemm_mfma<<<dim3(2, 38), blk, 0, stream>>>(h_in,   wtv, bv, buf_v, ROWS_, D_, D_, 0);
    // self attention (MFMA)
    self_attn_kernel<<<dim3(B_*NH_*5), blk, 0, stream>>>(buf_q, buf_k, buf_v, buf_sa);
    // output projection
    gemm_mfma<<<dim3(2, 38), blk, 0, stream>>>(buf_sa, wto, bo, buf_tmp, ROWS_, D_, D_, 0);
    // LN1: h1 = LN(h + sa2)
    ln_add_kernel<<<dim3(ROWS_/4), blk, 0, stream>>>(h_in, buf_tmp, ln1g, ln1b, buf_h1);
    // hp2 = h1 + pos
    add_kernel<<<dim3((n4+255)/256), blk, 0, stream>>>(buf_h1, pos, buf_hp, n4);
    // value projection (big GEMM): M = 134400 = 1050*128 exact
    gemm_mfma<<<dim3(2, 1050), blk, 0, stream>>>(ehs, wtval, b_val, buf_val, B_*S_, D_, D_, 0);
    // offsets + attention weights
    gemm_mfma<<<dim3(2, 38), blk, 0, stream>>>(buf_hp, wtoff, b_off, buf_q, ROWS_, 192, D_, 0);
    gemm_mfma<<<dim3(1, 38), blk, 0, stream>>>(buf_hp, wtaw,  b_aw,  buf_k, ROWS_, 96,  D_, 0);
    softmax12_kernel<<<dim3((ROWS_*NH_+255)/256), blk, 0, stream>>>(buf_k, ROWS_*NH_);
    // deformable sampling
    deform_kernel<<<dim3(NB_/256), blk, 0, stream>>>(buf_val, buf_q, buf_k, refp, buf_v);
    // ca projection
    gemm_mfma<<<dim3(2, 38), blk, 0, stream>>>(buf_v, wtout, b_out, buf_sa, ROWS_, D_, D_, 0);
    // LN2
    ln_add_kernel<<<dim3(ROWS_/4), blk, 0, stream>>>(buf_h1, buf_sa, ln2g, ln2b, buf_h2);
    // FFN
    gemm_mfma<<<dim3(8, 38), blk, 0, stream>>>(buf_h2, wtfc1, b_fc1, buf_fc1, ROWS_, FFN_, D_, 1);
    gemm_mfma<<<dim3(2, 38), blk, 0, stream>>>(buf_fc1, wtfc2, b_fc2, buf_tmp, ROWS_, D_, FFN_, 0);
    // LN3 -> out
    ln_add_kernel<<<dim3(ROWS_/4), blk, 0, stream>>>(buf_h2, buf_tmp, ln3g, ln3b, out);
}

// Round 5
// 312.251 us; speedup vs baseline: 4.6637x; 1.3380x over previous
//
#include <hip/hip_runtime.h>
#include <hip/hip_bf16.h>
#include <math.h>

// ---------------- problem constants ----------------
#define B_   16
#define NQ_  300
#define D_   256
#define NH_  8
#define DH_  32
#define L_   3
#define P_   4
#define FFN_ 1024
#define S_   8400   // 80*80 + 40*40 + 20*20
#define ROWS_ (B_*NQ_)        // 4800
#define NB_   (ROWS_*D_)      // 1228800 floats per (B,NQ,D) buffer

typedef __attribute__((ext_vector_type(4))) unsigned short ushort4_t;
typedef __attribute__((ext_vector_type(8))) unsigned short ushort8_t;
typedef __attribute__((ext_vector_type(8))) short bf16x8;
typedef __attribute__((ext_vector_type(4))) float f32x4;

__device__ inline unsigned short f2b(float f) {
    __hip_bfloat16 h = __float2bfloat16(f);
    return __builtin_bit_cast(unsigned short, h);
}
__device__ inline float b2f(unsigned short u) {
    union { unsigned u; float f; } c; c.u = ((unsigned)u) << 16; return c.f;
}

// ---------------- elementwise add (float4) ----------------
__global__ __launch_bounds__(256) void add_kernel(const float* __restrict__ a,
                                                  const float* __restrict__ b,
                                                  float* __restrict__ o, int n4) {
    int i = blockIdx.x * 256 + threadIdx.x;
    if (i < n4) {
        float4 va = ((const float4*)a)[i];
        float4 vb = ((const float4*)b)[i];
        float4 vo = {va.x+vb.x, va.y+vb.y, va.z+vb.z, va.w+vb.w};
        ((float4*)o)[i] = vo;
    }
}

// ---------------- concat two fp32 vectors ----------------
__global__ __launch_bounds__(256) void concat2_kernel(
    const float* __restrict__ a, int na, const float* __restrict__ b, int nb,
    float* __restrict__ dst)
{
    int i = blockIdx.x*256 + threadIdx.x;
    if (i < na) dst[i] = a[i];
    else if (i < na + nb) dst[i] = b[i - na];
}

// ---------------- weight transpose+cast: W (KxN fp32) -> WT (NxK bf16) --------
__global__ __launch_bounds__(256) void wtrans_kernel(
    const float* __restrict__ w, unsigned short* __restrict__ wt, int K, int N)
{
    __shared__ unsigned short t[32][33];
    int tid = threadIdx.x;
    int tx = tid & 31, ty = tid >> 5;           // ty 0..7
    int n0 = blockIdx.x * 32, k0 = blockIdx.y * 32;
    #pragma unroll
    for (int i = 0; i < 4; ++i) {
        int k = k0 + ty + i*8;
        int n = n0 + tx;
        t[tx][ty + i*8] = f2b(w[(size_t)k*N + n]);
    }
    __syncthreads();
    #pragma unroll
    for (int i = 0; i < 4; ++i) {
        int n = n0 + ty + i*8;
        int k = k0 + tx;
        wt[(size_t)n*K + k] = t[ty + i*8][tx];
    }
}

// ================= GEMM core macros (64x128 tile, 4 waves 2x2 of 32x64) =======
// staging: A thread t: row t>>2 (0..63), 8 floats at (t&3)*8
//          B thread t: row t>>1 (0..127), 16 bf16 at (t&1)*16
#define GEMM_PREAMBLE()                                                        \
    const int tid  = threadIdx.x;                                              \
    const int lane = tid & 63;                                                 \
    const int w    = tid >> 6;                                                 \
    const int wr   = w >> 1, wc = w & 1;                                       \
    const int m0   = blockIdx.y * 64;                                          \
    const int n0   = blockIdx.x * 128;                                         \
    const int fr   = lane & 15, fq = lane >> 4;                                \
    const int arow = tid >> 2, aseg = (tid & 3) * 8;                           \
    const int brow = tid >> 1, bseg = (tid & 1) * 16;                          \
    const bool a_ok = (m0 + arow) < M;                                         \
    const bool b_ok = (n0 + brow) < N;                                         \
    const float*          aptr = A  + (size_t)(m0 + arow)*K + aseg;            \
    const unsigned short* bptr = WT + (size_t)(n0 + brow)*K + bseg;            \
    f32x4 acc[2][4];                                                           \
    _Pragma("unroll") for (int m = 0; m < 2; ++m)                              \
        _Pragma("unroll") for (int n = 0; n < 4; ++n)                          \
            acc[m][n] = (f32x4){0.f, 0.f, 0.f, 0.f};                           \
    float4 avA0, avB0, avA1, avB1;                                             \
    ushort8_t bvA0, bvB0, bvA1, bvB1;

#define GEMM_LOAD(avA, avB, bvA, bvB, kk) do {                                 \
    if (a_ok) { avA = *(const float4*)(aptr + (kk));                           \
                avB = *(const float4*)(aptr + (kk) + 4); }                     \
    else { avA = (float4){0,0,0,0}; avB = (float4){0,0,0,0}; }                 \
    if (b_ok) { bvA = *(const ushort8_t*)(bptr + (kk));                        \
                bvB = *(const ushort8_t*)(bptr + (kk) + 8); }                  \
    else { _Pragma("unroll") for (int j = 0; j < 8; ++j){bvA[j]=0;bvB[j]=0;} } \
} while (0)

#define GEMM_STORE_LDS(avA, avB, bvA, bvB) do {                                \
    ushort8_t ac;                                                              \
    ac[0]=f2b(avA.x); ac[1]=f2b(avA.y); ac[2]=f2b(avA.z); ac[3]=f2b(avA.w);    \
    ac[4]=f2b(avB.x); ac[5]=f2b(avB.y); ac[6]=f2b(avB.z); ac[7]=f2b(avB.w);    \
    *(ushort8_t*)&As[arow][aseg]     = ac;                                     \
    *(ushort8_t*)&Bs[brow][bseg]     = bvA;                                    \
    *(ushort8_t*)&Bs[brow][bseg + 8] = bvB;                                    \
} while (0)

#define GEMM_COMPUTE() do {                                                    \
    bf16x8 af[2], bfv[4];                                                      \
    _Pragma("unroll") for (int m = 0; m < 2; ++m)                              \
        af[m] = *(const bf16x8*)&As[wr*32 + m*16 + fr][fq*8];                  \
    _Pragma("unroll") for (int n = 0; n < 4; ++n)                              \
        bfv[n] = *(const bf16x8*)&Bs[wc*64 + n*16 + fr][fq*8];                 \
    _Pragma("unroll") for (int m = 0; m < 2; ++m)                              \
        _Pragma("unroll") for (int n = 0; n < 4; ++n)                          \
            acc[m][n] = __builtin_amdgcn_mfma_f32_16x16x32_bf16(               \
                af[m], bfv[n], acc[m][n], 0, 0, 0);                            \
} while (0)

// pipelined K loop: loads for next half-step issued before compute
#define GEMM_KLOOP()                                                           \
    GEMM_LOAD(avA0, avB0, bvA0, bvB0, 0);                                      \
    for (int k0 = 0; k0 < K; k0 += 64) {                                       \
        __syncthreads();                                                       \
        GEMM_STORE_LDS(avA0, avB0, bvA0, bvB0);                                \
        GEMM_LOAD(avA1, avB1, bvA1, bvB1, k0 + 32);                            \
        __syncthreads();                                                       \
        GEMM_COMPUTE();                                                        \
        __syncthreads();                                                       \
        GEMM_STORE_LDS(avA1, avB1, bvA1, bvB1);                                \
        if (k0 + 64 < K) GEMM_LOAD(avA0, avB0, bvA0, bvB0, k0 + 64);           \
        __syncthreads();                                                       \
        GEMM_COMPUTE();                                                        \
    }

// ---------------- generic GEMM: C(MxN fp32) = A(MxK fp32) @ WT^T + bias -------
__global__ __launch_bounds__(256) void gemm_mfma64(
    const float* __restrict__ A, const unsigned short* __restrict__ WT,
    const float* __restrict__ bias, float* __restrict__ C,
    int M, int N, int K, int relu)
{
    __shared__ unsigned short As[64][40];
    __shared__ unsigned short Bs[128][40];
    GEMM_PREAMBLE();
    GEMM_KLOOP();

    #pragma unroll
    for (int n = 0; n < 4; ++n) {
        int col = n0 + wc*64 + n*16 + fr;
        if (col < N) {
            float bcol = bias[col];
            #pragma unroll
            for (int m = 0; m < 2; ++m) {
                int rbase = m0 + wr*32 + m*16 + fq*4;
                #pragma unroll
                for (int r = 0; r < 4; ++r) {
                    int row = rbase + r;
                    if (row < M) {
                        float vv = acc[m][n][r] + bcol;
                        if (relu) vv = fmaxf(vv, 0.f);
                        C[(size_t)row * N + col] = vv;
                    }
                }
            }
        }
    }
}

// ---------------- value GEMM: out bf16, head-major [b][h][s][32] --------------
__global__ __launch_bounds__(256) void gemm_val(
    const float* __restrict__ A, const unsigned short* __restrict__ WT,
    const float* __restrict__ bias, unsigned short* __restrict__ OUT,
    int M, int N, int K)
{
    __shared__ unsigned short As[64][40];
    __shared__ unsigned short Bs[128][40];
    GEMM_PREAMBLE();
    GEMM_KLOOP();

    #pragma unroll
    for (int n = 0; n < 4; ++n) {
        int col = n0 + wc*64 + n*16 + fr;      // 0..255
        int hh = col >> 5, dd = col & 31;
        float bcol = bias[col];
        #pragma unroll
        for (int m = 0; m < 2; ++m) {
            int rbase = m0 + wr*32 + m*16 + fq*4;
            #pragma unroll
            for (int r = 0; r < 4; ++r) {
                unsigned row = rbase + r;          // 0..134399
                unsigned bb = row / (unsigned)S_;
                unsigned ss = row - bb * (unsigned)S_;
                OUT[((size_t)(bb*NH_ + hh)*S_ + ss)*DH_ + dd] = f2b(acc[m][n][r] + bcol);
            }
        }
    }
}

// ---------------- self attention via MFMA ----------------
// q,k live in fused buf_qk (row stride 512: q cols 0..255, k cols 256..511)
// grid.x = B*NH*5 = 640; block 256 = 4 waves; each wave: 16 queries.
__global__ __launch_bounds__(256) void self_attn_kernel(
    const float* __restrict__ qk, const float* __restrict__ v,
    float* __restrict__ sa)
{
    __shared__ unsigned short k_sw[304*32];      // K bf16, 16B-unit XOR swizzled
    __shared__ unsigned short vt[32][312];       // V^T bf16: [d][key]
    __shared__ unsigned short p_all[4][16][312]; // per-wave P: [q_local][key]

    const int bid  = blockIdx.x;
    const int part = bid % 5;
    const int bh   = bid / 5;
    const int h    = bh & 7;
    const int b    = bh >> 3;
    const int tid  = threadIdx.x;
    const int lane = tid & 63;
    const int w    = tid >> 6;
    const int g    = lane >> 4;   // 0..3
    const int fr   = lane & 15;

    const size_t qbase = (size_t)b*NQ_*512 + h*DH_;        // q cols
    const size_t kbase = qbase + 256;                      // k cols
    const size_t vbase = (size_t)b*NQ_*D_ + h*DH_;
    const size_t sbase = (size_t)b*NQ_*D_ + h*DH_;

    // ---- stage K: rows 0..303 (zero-pad >=300), swizzle 16B unit u^=(r>>1)&3 ----
    for (int i = tid; i < 1216; i += 256) {
        int r = i >> 2, u = i & 3;
        ushort8_t kb;
        if (r < NQ_) {
            const float* p8 = qk + kbase + (size_t)r*512 + u*8;
            float4 a0 = *(const float4*)p8;
            float4 a1 = *(const float4*)(p8 + 4);
            kb[0]=f2b(a0.x); kb[1]=f2b(a0.y); kb[2]=f2b(a0.z); kb[3]=f2b(a0.w);
            kb[4]=f2b(a1.x); kb[5]=f2b(a1.y); kb[6]=f2b(a1.z); kb[7]=f2b(a1.w);
        } else {
            #pragma unroll
            for (int j = 0; j < 8; ++j) kb[j] = 0;
        }
        int su = u ^ ((r >> 1) & 3);
        *(ushort8_t*)&k_sw[r*32 + su*8] = kb;
    }
    // ---- stage V transposed: vt[d][key] ----
    for (int i = tid; i < 1216; i += 256) {
        int kk = i >> 2, u = i & 3;
        if (kk < NQ_) {
            const float* p8 = v + vbase + (size_t)kk*D_ + u*8;
            float4 a0 = *(const float4*)p8;
            float4 a1 = *(const float4*)(p8 + 4);
            float f[8] = {a0.x,a0.y,a0.z,a0.w,a1.x,a1.y,a1.z,a1.w};
            #pragma unroll
            for (int j = 0; j < 8; ++j) vt[u*8 + j][kk] = f2b(f[j]);
        } else {
            #pragma unroll
            for (int j = 0; j < 8; ++j) vt[u*8 + j][kk] = 0;
        }
    }
    __syncthreads();

    // ---- Q fragment: q_local = fr, k-range = g*8..g*8+7, pre-scaled ----
    const int q0 = part*64 + w*16;
    const int qi = q0 + fr;
    bf16x8 qf;
    if (qi < NQ_) {
        const float scale = 0.17677669529663687f;   // 1/sqrt(32)
        const float* p8 = qk + qbase + (size_t)qi*512 + g*8;
        float4 a0 = *(const float4*)p8;
        float4 a1 = *(const float4*)(p8 + 4);
        qf[0]=(short)f2b(a0.x*scale); qf[1]=(short)f2b(a0.y*scale);
        qf[2]=(short)f2b(a0.z*scale); qf[3]=(short)f2b(a0.w*scale);
        qf[4]=(short)f2b(a1.x*scale); qf[5]=(short)f2b(a1.y*scale);
        qf[6]=(short)f2b(a1.z*scale); qf[7]=(short)f2b(a1.w*scale);
    } else {
        #pragma unroll
        for (int j = 0; j < 8; ++j) qf[j] = 0;
    }

    // ---- QK^T: 19 key-tiles; S^T tile: row=key(g*4+r), col=query(fr) ----
    const int ksw_u = g ^ ((fr >> 1) & 3);
    f32x4 acc[19];
    #pragma unroll
    for (int t = 0; t < 19; ++t) acc[t] = (f32x4){0.f,0.f,0.f,0.f};
    #pragma unroll
    for (int t = 0; t < 19; ++t) {
        int row = t*16 + fr;
        bf16x8 kf = *(const bf16x8*)&k_sw[row*32 + ksw_u*8];
        acc[t] = __builtin_amdgcn_mfma_f32_16x16x32_bf16(kf, qf, acc[t], 0, 0, 0);
    }
    if (g == 3) acc[18] = (f32x4){-1e30f, -1e30f, -1e30f, -1e30f};

    // ---- softmax per query column ----
    float m = -1e30f;
    #pragma unroll
    for (int t = 0; t < 19; ++t) {
        #pragma unroll
        for (int r = 0; r < 4; ++r) m = fmaxf(m, acc[t][r]);
    }
    m = fmaxf(m, __shfl_xor(m, 16));
    m = fmaxf(m, __shfl_xor(m, 32));
    float lsum = 0.f;
    #pragma unroll
    for (int t = 0; t < 19; ++t) {
        #pragma unroll
        for (int r = 0; r < 4; ++r) {
            float e = __expf(acc[t][r] - m);
            acc[t][r] = e;
            lsum += e;
        }
    }
    lsum += __shfl_xor(lsum, 16);
    lsum += __shfl_xor(lsum, 32);
    float inv = 1.0f / lsum;

    // ---- P -> LDS (bf16, normalized). key of acc[t][r] = t*16 + g*4 + r ----
    #pragma unroll
    for (int t = 0; t < 19; ++t) {
        ushort4_t pw = { f2b(acc[t][0]*inv), f2b(acc[t][1]*inv),
                         f2b(acc[t][2]*inv), f2b(acc[t][3]*inv) };
        *(ushort4_t*)&p_all[w][fr][t*16 + g*4] = pw;
    }

    // ---- PV: out[16 q][32 d]; k-steps of 32 over 304 keys ----
    f32x4 o0 = (f32x4){0.f,0.f,0.f,0.f};
    f32x4 o1 = (f32x4){0.f,0.f,0.f,0.f};
    #pragma unroll
    for (int ks = 0; ks < 10; ++ks) {
        int kb = ks*32 + g*8;
        bf16x8 pf, vf0, vf1;
        if (kb < 304) {
            pf  = *(const bf16x8*)&p_all[w][fr][kb];
            vf0 = *(const bf16x8*)&vt[fr][kb];
            vf1 = *(const bf16x8*)&vt[16 + fr][kb];
        } else {
            #pragma unroll
            for (int j = 0; j < 8; ++j) { pf[j] = 0; vf0[j] = 0; vf1[j] = 0; }
        }
        o0 = __builtin_amdgcn_mfma_f32_16x16x32_bf16(pf, vf0, o0, 0, 0, 0);
        o1 = __builtin_amdgcn_mfma_f32_16x16x32_bf16(pf, vf1, o1, 0, 0, 0);
    }

    #pragma unroll
    for (int r = 0; r < 4; ++r) {
        int qo = q0 + g*4 + r;
        if (qo < NQ_) {
            sa[sbase + (size_t)qo*D_ + fr]      = o0[r];
            sa[sbase + (size_t)qo*D_ + 16 + fr] = o1[r];
        }
    }
}

// ---------------- LayerNorm(x + y) ----------------
__global__ __launch_bounds__(256) void ln_add_kernel(
    const float* __restrict__ x, const float* __restrict__ y,
    const float* __restrict__ g, const float* __restrict__ bb,
    float* __restrict__ out)
{
    int w = threadIdx.x >> 6, lane = threadIdx.x & 63;
    int row = blockIdx.x*4 + w;
    const float* xr = x + (size_t)row*D_;
    const float* yr = y + (size_t)row*D_;
    float vals[4];
    float s = 0.f;
    #pragma unroll
    for (int i = 0; i < 4; i++) { vals[i] = xr[lane + 64*i] + yr[lane + 64*i]; s += vals[i]; }
    #pragma unroll
    for (int off = 32; off; off >>= 1) s += __shfl_xor(s, off);
    float mean = s * (1.0f/D_);
    float vs = 0.f;
    #pragma unroll
    for (int i = 0; i < 4; i++) { float dd = vals[i]-mean; vs += dd*dd; }
    #pragma unroll
    for (int off = 32; off; off >>= 1) vs += __shfl_xor(vs, off);
    float rstd = rsqrtf(vs*(1.0f/D_) + 1e-5f);
    #pragma unroll
    for (int i = 0; i < 4; i++) {
        int c = lane + 64*i;
        out[(size_t)row*D_ + c] = (vals[i]-mean)*rstd*g[c] + bb[c];
    }
}

// ---------------- softmax over 12 per (b,q,h), in fused off/aw buffer --------
// oa row layout: [B*NQ][288]: cols 0..191 = off, 192..287 = aw (8 heads x 12)
__global__ __launch_bounds__(256) void softmax12_oa(float* __restrict__ oa)
{
    int r = blockIdx.x*256 + threadIdx.x;
    if (r >= ROWS_*NH_) return;
    float* p = oa + (size_t)(r >> 3)*288 + 192 + (r & 7)*12;
    float v[12];
    float m = -1e30f;
    #pragma unroll
    for (int i = 0; i < 12; i++) { v[i] = p[i]; m = fmaxf(m, v[i]); }
    float s = 0.f;
    #pragma unroll
    for (int i = 0; i < 12; i++) { v[i] = __expf(v[i]-m); s += v[i]; }
    float inv = 1.f/s;
    #pragma unroll
    for (int i = 0; i < 12; i++) p[i] = v[i]*inv;
}

// ---------------- deformable bilinear sampling (bf16 head-major value) -------
// value layout: [b][h][s][32] bf16. one thread per (b,q,h,d).
__global__ __launch_bounds__(256) void deform_kernel(
    const unsigned short* __restrict__ value, const float* __restrict__ oa,
    const float* __restrict__ refp, float* __restrict__ dout)
{
    int gid = blockIdx.x*256 + threadIdx.x;
    int d = gid & 31;
    int h = (gid >> 5) & 7;
    int bq = gid >> 8;
    int qq = bq % NQ_;
    int b  = bq / NQ_;

    const int starts[3] = {0, 6400, 8000};
    const int Hs[3] = {80, 40, 20};

    const float* offp = oa + (size_t)(b*NQ_+qq)*288 + h*24;
    const float* awp  = oa + (size_t)(b*NQ_+qq)*288 + 192 + h*12;
    const float* refq = refp + (size_t)(b*NQ_+qq)*(L_*2);
    const unsigned short* vb = value + ((size_t)(b*NH_ + h)*S_)*DH_ + d;

    float acc = 0.f;
    #pragma unroll
    for (int l = 0; l < L_; l++) {
        int Hl = Hs[l], Wl = Hs[l];
        float rx = refq[l*2+0], ry = refq[l*2+1];
        const unsigned short* vlb = vb + (size_t)starts[l]*DH_;
        #pragma unroll
        for (int p = 0; p < P_; p++) {
            float ox = offp[(l*P_+p)*2+0], oy = offp[(l*P_+p)*2+1];
            float a  = awp[l*P_+p];
            float x = (rx + ox/(float)Wl)*(float)Wl - 0.5f;
            float y = (ry + oy/(float)Hl)*(float)Hl - 0.5f;
            float x0 = floorf(x), y0 = floorf(y);
            #pragma unroll
            for (int dy = 0; dy < 2; dy++) {
                #pragma unroll
                for (int dx = 0; dx < 2; dx++) {
                    float xi = x0 + dx, yi = y0 + dy;
                    float wgt = (1.f - fabsf(x-xi))*(1.f - fabsf(y-yi));
                    bool valid = (xi >= 0.f) && (xi < (float)Wl) && (yi >= 0.f) && (yi < (float)Hl);
                    if (valid && wgt != 0.f) {
                        int ix = (int)xi, iy = (int)yi;
                        acc += a * wgt * b2f(vlb[(size_t)(iy*Wl + ix)*DH_]);
                    }
                }
            }
        }
    }
    dout[gid] = acc;
}

// ---------------- launch ----------------
extern "C" void kernel_launch(void* const* d_in, const int* in_sizes, int n_in,
                              void* d_out, int out_size, void* d_ws, size_t ws_size,
                              hipStream_t stream) {
    (void)in_sizes; (void)n_in; (void)out_size; (void)ws_size;
    const float* h_in  = (const float*)d_in[0];
    const float* pos   = (const float*)d_in[1];
    const float* ehs   = (const float*)d_in[2];
    const float* refp  = (const float*)d_in[3];
    // d_in[4] = spatial_shapes (hardcoded)
    const float* wq    = (const float*)d_in[5];
    const float* bq    = (const float*)d_in[6];
    const float* wk    = (const float*)d_in[7];
    const float* bk    = (const float*)d_in[8];
    const float* wv    = (const float*)d_in[9];
    const float* bv    = (const float*)d_in[10];
    const float* wo    = (const float*)d_in[11];
    const float* bo    = (const float*)d_in[12];
    const float* ln1g  = (const float*)d_in[13];
    const float* ln1b  = (const float*)d_in[14];
    const float* w_off = (const float*)d_in[15];
    const float* b_off = (const float*)d_in[16];
    const float* w_aw  = (const float*)d_in[17];
    const float* b_aw  = (const float*)d_in[18];
    const float* w_val = (const float*)d_in[19];
    const float* b_val = (const float*)d_in[20];
    const float* w_out = (const float*)d_in[21];
    const float* b_out = (const float*)d_in[22];
    const float* ln2g  = (const float*)d_in[23];
    const float* ln2b  = (const float*)d_in[24];
    const float* w_fc1 = (const float*)d_in[25];
    const float* b_fc1 = (const float*)d_in[26];
    const float* w_fc2 = (const float*)d_in[27];
    const float* b_fc2 = (const float*)d_in[28];
    const float* ln3g  = (const float*)d_in[29];
    const float* ln3b  = (const float*)d_in[30];
    float* out = (float*)d_out;

    float* ws = (float*)d_ws;
    float* buf_hp   = ws + 0*(size_t)NB_;          // hp / hp2
    float* buf_qk   = ws + 1*(size_t)NB_;          // fused q|k, 4800x512 (2 NB)
    float* buf_v    = ws + 3*(size_t)NB_;          // v proj; later deform out
    float* buf_sa   = ws + 4*(size_t)NB_;          // sa; later ca
    float* buf_tmp  = ws + 5*(size_t)NB_;          // wo out / mlp out
    float* buf_h1   = ws + 6*(size_t)NB_;
    float* buf_h2   = ws + 7*(size_t)NB_;
    float* buf_oa   = ws + 8*(size_t)NB_;          // fused off|aw, 4800x288 (1.5 NB)
    float* buf_fc1  = ws + 9*(size_t)NB_ + NB_/2;  // 4800x1024 (4 NB)
    unsigned short* val_bf = (unsigned short*)(ws + 13*(size_t)NB_ + NB_/2);  // 34,406,400 us (14 NB)

    unsigned short* wtb = (unsigned short*)(ws + 27*(size_t)NB_ + NB_/2);
    unsigned short* wtqk  = wtb;                   // 512x256
    unsigned short* wtv   = wtqk  + 131072;        // 256x256
    unsigned short* wto   = wtv   + 65536;
    unsigned short* wtval = wto   + 65536;
    unsigned short* wtout = wtval + 65536;
    unsigned short* wtoa  = wtout + 65536;         // 288x256
    unsigned short* wtfc1 = wtoa  + 73728;         // 1024x256
    unsigned short* wtfc2 = wtfc1 + 262144;        // 256x1024
    float* bqk = (float*)(wtfc2 + 262144);         // 512
    float* boa = bqk + 512;                        // 288

    const int n4 = NB_/4;
    dim3 blk(256);

    // ---- weight prep (transpose + bf16 cast; fused QK and OFF|AW regions) ----
    wtrans_kernel<<<dim3(8, 8),  blk, 0, stream>>>(wq,    wtqk,          D_, D_);
    wtrans_kernel<<<dim3(8, 8),  blk, 0, stream>>>(wk,    wtqk + 65536,  D_, D_);
    wtrans_kernel<<<dim3(8, 8),  blk, 0, stream>>>(wv,    wtv,           D_, D_);
    wtrans_kernel<<<dim3(8, 8),  blk, 0, stream>>>(wo,    wto,           D_, D_);
    wtrans_kernel<<<dim3(8, 8),  blk, 0, stream>>>(w_val, wtval,         D_, D_);
    wtrans_kernel<<<dim3(8, 8),  blk, 0, stream>>>(w_out, wtout,         D_, D_);
    wtrans_kernel<<<dim3(6, 8),  blk, 0, stream>>>(w_off, wtoa,          D_, 192);
    wtrans_kernel<<<dim3(3, 8),  blk, 0, stream>>>(w_aw,  wtoa + 49152,  D_, 96);
    wtrans_kernel<<<dim3(32, 8), blk, 0, stream>>>(w_fc1, wtfc1,         D_, FFN_);
    wtrans_kernel<<<dim3(8, 32), blk, 0, stream>>>(w_fc2, wtfc2,         FFN_, D_);
    concat2_kernel<<<dim3(2), blk, 0, stream>>>(bq, 256, bk, 256, bqk);
    concat2_kernel<<<dim3(2), blk, 0, stream>>>(b_off, 192, b_aw, 96, boa);

    // hp = h + pos
    add_kernel<<<dim3((n4+255)/256), blk, 0, stream>>>(h_in, pos, buf_hp, n4);
    // fused QK projection (N=512) + V projection
    gemm_mfma64<<<dim3(4, 75), blk, 0, stream>>>(buf_hp, wtqk, bqk, buf_qk, ROWS_, 512, D_, 0);
    gemm_mfma64<<<dim3(2, 75), blk, 0, stream>>>(h_in,   wtv,  bv,  buf_v,  ROWS_, D_,  D_, 0);
    // self attention (MFMA)
    self_attn_kernel<<<dim3(B_*NH_*5), blk, 0, stream>>>(buf_qk, buf_v, buf_sa);
    // output projection
    gemm_mfma64<<<dim3(2, 75), blk, 0, stream>>>(buf_sa, wto, bo, buf_tmp, ROWS_, D_, D_, 0);
    // LN1: h1 = LN(h + sa2)
    ln_add_kernel<<<dim3(ROWS_/4), blk, 0, stream>>>(h_in, buf_tmp, ln1g, ln1b, buf_h1);
    // hp2 = h1 + pos
    add_kernel<<<dim3((n4+255)/256), blk, 0, stream>>>(buf_h1, pos, buf_hp, n4);
    // value projection -> bf16 head-major [b][h][s][32]
    gemm_val<<<dim3(2, 2100), blk, 0, stream>>>(ehs, wtval, b_val, val_bf, B_*S_, D_, D_);
    // fused offsets + attention weights (N=288)
    gemm_mfma64<<<dim3(3, 75), blk, 0, stream>>>(buf_hp, wtoa, boa, buf_oa, ROWS_, 288, D_, 0);
    softmax12_oa<<<dim3((ROWS_*NH_+255)/256), blk, 0, stream>>>(buf_oa);
    // deformable sampling
    deform_kernel<<<dim3(NB_/256), blk, 0, stream>>>(val_bf, buf_oa, refp, buf_v);
    // ca projection
    gemm_mfma64<<<dim3(2, 75), blk, 0, stream>>>(buf_v, wtout, b_out, buf_sa, ROWS_, D_, D_, 0);
    // LN2
    ln_add_kernel<<<dim3(ROWS_/4), blk, 0, stream>>>(buf_h1, buf_sa, ln2g, ln2b, buf_h2);
    // FFN
    gemm_mfma64<<<dim3(8, 75), blk, 0, stream>>>(buf_h2, wtfc1, b_fc1, buf_fc1, ROWS_, FFN_, D_, 1);
    gemm_mfma64<<<dim3(2, 75), blk, 0, stream>>>(buf_fc1, wtfc2, b_fc2, buf_tmp, ROWS_, D_, FFN_, 0);
    // LN3 -> out
    ln_add_kernel<<<dim3(ROWS_/4), blk, 0, stream>>>(buf_h2, buf_tmp, ln3g, ln3b, out);
}